// Round 8
// baseline (145.013 us; speedup 1.0000x reference)
//
#include <hip/hip_runtime.h>
#include <hip/hip_bf16.h>

// MoE top-2 + shared expert, bf16 MFMA path. Round 8.
// vs R7 (125.9us): transpose_all rewritten as a pure REGISTER transpose —
// each lane owns one output row; column reads are wave-coalesced (256B/instr),
// packed bf16 written as 8x uint4 per lane (L2 merges the 16B segments into
// full lines). No LDS, no barrier (R7 profile: 48us, 8-way LDS write conflicts,
// 5% VALU, 29% HBM = LDS-op/latency bound). GEMMs unchanged (512thr/8wave won).

#define DIM 1024
#define NTOK 2048
#define NEXP 8
#define NENT 4096          // NTOK * 2
#define ROWS_CAP 8192      // padded grouped rows upper bound
#define MAX_TILES 64
#define MM (DIM * DIM)

typedef float f32x4 __attribute__((ext_vector_type(4)));
typedef __bf16 bf16x8 __attribute__((ext_vector_type(8)));

__device__ __forceinline__ unsigned short f2bf(float f) {
  unsigned int u = __builtin_bit_cast(unsigned int, f);
  unsigned int r = u + 0x7FFFu + ((u >> 16) & 1u);   // RNE
  return (unsigned short)(r >> 16);
}
__device__ __forceinline__ void gload_lds16(const unsigned short* g, unsigned short* l) {
  __builtin_amdgcn_global_load_lds((__attribute__((address_space(1))) const void*)g,
                                   (__attribute__((address_space(3))) void*)l, 16, 0, 0);
}

// ---------------- x -> bf16 (row NTOK is an all-zero pad row) ----------------------------------
__global__ __launch_bounds__(256) void cast_x(const float* __restrict__ x,
                                              unsigned short* __restrict__ xbf) {
  int r = blockIdx.x;                 // 0..NTOK
  int c = threadIdx.x * 4;
  ushort4 o;
  if (r < NTOK) {
    float4 v = *(const float4*)(x + (size_t)r * DIM + c);
    o.x = f2bf(v.x); o.y = f2bf(v.y); o.z = f2bf(v.z); o.w = f2bf(v.w);
  } else {
    o.x = o.y = o.z = o.w = 0;
  }
  *(ushort4*)(xbf + (size_t)r * DIM + c) = o;
}

// ---------------- weight transpose+cast, register-only: dst[n][k] = bf16(src[k][n]) -----------
// Wave-tile 64n x 64k. Lane owns output row n=c0+lane: 64 coalesced column
// reads (256B/instruction across the wave), pack pairs, 8x uint4 stores.
__global__ __launch_bounds__(256) void transpose_all(
    const float* __restrict__ w1, const float* __restrict__ w3, const float* __restrict__ w2,
    const float* __restrict__ w1s, const float* __restrict__ w3s, const float* __restrict__ w2s,
    unsigned short* __restrict__ w1t, unsigned short* __restrict__ w3t,
    unsigned short* __restrict__ w2t, unsigned short* __restrict__ w1st,
    unsigned short* __restrict__ w3st, unsigned short* __restrict__ w2st) {
  int z = blockIdx.z;
  const float* src; unsigned short* dst;
  if (z < 8)       { src = w1 + (size_t)z * MM;        dst = w1t + (size_t)z * MM; }
  else if (z < 16) { src = w3 + (size_t)(z - 8) * MM;  dst = w3t + (size_t)(z - 8) * MM; }
  else if (z < 24) { src = w2 + (size_t)(z - 16) * MM; dst = w2t + (size_t)(z - 16) * MM; }
  else if (z == 24){ src = w1s; dst = w1st; }
  else if (z == 25){ src = w3s; dst = w3st; }
  else             { src = w2s; dst = w2st; }

  int wave = threadIdx.x >> 6, lane = threadIdx.x & 63;
  int tile = blockIdx.x * 4 + wave;          // 0..255
  int c0 = (tile & 15) * 64;                 // n origin
  int r0 = (tile >> 4) * 64;                 // k origin
  const float* s = src + (size_t)r0 * DIM + c0 + lane;
  unsigned short* d = dst + (size_t)(c0 + lane) * DIM + r0;

#pragma unroll
  for (int j = 0; j < 8; j++) {
    float v0 = s[(size_t)(j * 8 + 0) * DIM];
    float v1 = s[(size_t)(j * 8 + 1) * DIM];
    float v2 = s[(size_t)(j * 8 + 2) * DIM];
    float v3 = s[(size_t)(j * 8 + 3) * DIM];
    float v4 = s[(size_t)(j * 8 + 4) * DIM];
    float v5 = s[(size_t)(j * 8 + 5) * DIM];
    float v6 = s[(size_t)(j * 8 + 6) * DIM];
    float v7 = s[(size_t)(j * 8 + 7) * DIM];
    uint4 p;
    p.x = f2bf(v0) | ((unsigned int)f2bf(v1) << 16);
    p.y = f2bf(v2) | ((unsigned int)f2bf(v3) << 16);
    p.z = f2bf(v4) | ((unsigned int)f2bf(v5) << 16);
    p.w = f2bf(v6) | ((unsigned int)f2bf(v7) << 16);
    *(uint4*)(d + j * 8) = p;
  }
}

// ---------------- router: fp32 logits -> softmax -> top-2 --------------------------------------
__global__ __launch_bounds__(64) void router(const float* __restrict__ x,
                                             const float* __restrict__ gw,
                                             int* __restrict__ e0, int* __restrict__ e1,
                                             float* __restrict__ s0, float* __restrict__ s1) {
  int t = blockIdx.x;
  int lane = threadIdx.x;
  const float* xr = x + (size_t)t * DIM;
  float acc[NEXP];
#pragma unroll
  for (int e = 0; e < NEXP; e++) acc[e] = 0.f;
  for (int i = 0; i < DIM / 64; i++) {
    float xv = xr[i * 64 + lane];
#pragma unroll
    for (int e = 0; e < NEXP; e++) acc[e] += xv * gw[e * DIM + i * 64 + lane];
  }
#pragma unroll
  for (int e = 0; e < NEXP; e++) {
    float v = acc[e];
    for (int o = 32; o > 0; o >>= 1) v += __shfl_xor(v, o);
    acc[e] = v;
  }
  if (lane == 0) {
    float m = acc[0];
#pragma unroll
    for (int e = 1; e < NEXP; e++) m = fmaxf(m, acc[e]);
    float ex[NEXP]; float Z = 0.f;
#pragma unroll
    for (int e = 0; e < NEXP; e++) { ex[e] = __expf(acc[e] - m); Z += ex[e]; }
    float inv = 1.f / Z;
    float sc[NEXP];
#pragma unroll
    for (int e = 0; e < NEXP; e++) sc[e] = ex[e] * inv;
    int b0 = 0; float v0 = sc[0];
#pragma unroll
    for (int e = 1; e < NEXP; e++) if (sc[e] > v0) { v0 = sc[e]; b0 = e; }
    int b1 = -1; float v1 = -1.f;
#pragma unroll
    for (int e = 0; e < NEXP; e++) if (e != b0 && sc[e] > v1) { v1 = sc[e]; b1 = e; }
    e0[t] = b0; e1[t] = b1; s0[t] = v0; s1[t] = v1;
  }
}

// ---------------- deterministic grouped build: packed uint4 scan (128-row padding) -------------
__global__ __launch_bounds__(256) void build_groups(
    const int* __restrict__ e0, const int* __restrict__ e1,
    const float* __restrict__ s0, const float* __restrict__ s1,
    int* __restrict__ gtok, float* __restrict__ gsc, int* __restrict__ row_of,
    int* __restrict__ tile_e, int* __restrict__ tile_r0, int* __restrict__ ntiles,
    int* __restrict__ base8out) {
  __shared__ unsigned int wsum[4][4];
  __shared__ int offl[256][NEXP];
  __shared__ int lrl[256][NEXP];
  int t = threadIdx.x, lane = t & 63, wave = t >> 6;

  for (int i = t; i < ROWS_CAP; i += 256) { gtok[i] = NTOK; gsc[i] = 0.f; }  // pad -> zero row

  unsigned int pc[4] = {0, 0, 0, 0};
#pragma unroll
  for (int i = 0; i < 16; i++) {
    int ent = t * 16 + i;
    int tok = ent >> 1;
    int e = (ent & 1) ? e1[tok] : e0[tok];
    unsigned int add = 1u << ((e & 1) * 16);
    int c = e >> 1;
    if (c == 0) pc[0] += add; else if (c == 1) pc[1] += add;
    else if (c == 2) pc[2] += add; else pc[3] += add;
  }
  unsigned int incl[4] = {pc[0], pc[1], pc[2], pc[3]};
#pragma unroll
  for (int o = 1; o < 64; o <<= 1) {
    unsigned int u0 = __shfl_up(incl[0], o), u1 = __shfl_up(incl[1], o);
    unsigned int u2 = __shfl_up(incl[2], o), u3 = __shfl_up(incl[3], o);
    if (lane >= o) { incl[0] += u0; incl[1] += u1; incl[2] += u2; incl[3] += u3; }
  }
  if (lane == 63) { wsum[wave][0] = incl[0]; wsum[wave][1] = incl[1];
                    wsum[wave][2] = incl[2]; wsum[wave][3] = incl[3]; }
  __syncthreads();
  unsigned int T[4], pre[4] = {0, 0, 0, 0};
#pragma unroll
  for (int c = 0; c < 4; c++)
    T[c] = wsum[0][c] + wsum[1][c] + wsum[2][c] + wsum[3][c];
#pragma unroll
  for (int w = 0; w < 3; w++)
    if (wave > w) { pre[0] += wsum[w][0]; pre[1] += wsum[w][1];
                    pre[2] += wsum[w][2]; pre[3] += wsum[w][3]; }
  int base[NEXP + 1];
  {
    int b = 0;
#pragma unroll
    for (int e = 0; e < NEXP; e++) {
      int tot = (int)((T[e >> 1] >> ((e & 1) * 16)) & 0xFFFFu);
      base[e] = b; b += (tot + 127) & ~127;
    }
    base[NEXP] = b;
  }
#pragma unroll
  for (int e = 0; e < NEXP; e++) {
    unsigned int ex = (incl[e >> 1] + pre[e >> 1] - pc[e >> 1]);
    offl[t][e] = (int)((ex >> ((e & 1) * 16)) & 0xFFFFu);
    lrl[t][e] = 0;
  }
  if (t == 0) {
    int nt = 0;
#pragma unroll
    for (int e = 0; e < NEXP; e++) {
      int tot = (int)((T[e >> 1] >> ((e & 1) * 16)) & 0xFFFFu);
      int ntl = (tot + 127) >> 7;
      for (int i = 0; i < ntl; i++) { tile_e[nt] = e; tile_r0[nt] = base[e] + i * 128; nt++; }
    }
    for (int i = 0; i < NTOK / 128; i++) { tile_e[nt] = NEXP; tile_r0[nt] = base[NEXP] + i * 128; nt++; }
    *ntiles = nt;
    *base8out = base[NEXP];
  }
  __syncthreads();   // gtok/gsc clear complete before scatter

#pragma unroll
  for (int i = 0; i < 16; i++) {
    int ent = t * 16 + i;
    int tok = ent >> 1;
    int k = ent & 1;
    int e = k ? e1[tok] : e0[tok];
    float s = k ? s1[tok] : s0[tok];
    int pos = base[e] + offl[t][e] + lrl[t][e];
    lrl[t][e]++;
    gtok[pos] = tok; gsc[pos] = s; row_of[ent] = pos;
  }
  for (int i = t; i < NTOK; i += 256) { gtok[base[NEXP] + i] = i; gsc[base[NEXP] + i] = 1.0f; }
}

// ------- fused grouped GEMM: h = silu(s*(A*W1_e)) * (s*(A*W3_e)), A gathered from xbf ----------
// 512 threads / 8 waves on a 128x128 tile; wave-tile 32x64; 3 gloads/thread/step.
__global__ __launch_bounds__(512, 4) void gemm13(
    const unsigned short* __restrict__ xbf,
    const unsigned short* __restrict__ W1, const unsigned short* __restrict__ W1s,
    const unsigned short* __restrict__ W3, const unsigned short* __restrict__ W3s,
    unsigned short* __restrict__ H,
    const int* __restrict__ gtok, const float* __restrict__ gsc,
    const int* __restrict__ tile_e, const int* __restrict__ tile_r0,
    const int* __restrict__ ntiles) {
  if ((int)blockIdx.y >= *ntiles) return;
  int e = tile_e[blockIdx.y];
  int row0 = tile_r0[blockIdx.y];
  int col0 = blockIdx.x * 128;
  const unsigned short* B1 = (e < NEXP) ? (W1 + (size_t)e * MM) : W1s;
  const unsigned short* B3 = (e < NEXP) ? (W3 + (size_t)e * MM) : W3s;

  __shared__ __align__(16) unsigned short As[128 * 32];    // 8KB
  __shared__ __align__(16) unsigned short Bs1[128 * 32];   // 8KB
  __shared__ __align__(16) unsigned short Bs3[128 * 32];   // 8KB
  __shared__ float ss[128];

  int tid = threadIdx.x;
  int wave = tid >> 6, lane = tid & 63;
  int wrow = (wave & 3) * 32, wcol = (wave >> 2) * 64;

  if (tid < 128) ss[tid] = gsc[row0 + tid];   // synced by first K-loop barrier

  f32x4 acc1[2][4], acc3[2][4];
#pragma unroll
  for (int m = 0; m < 2; m++)
#pragma unroll
    for (int n = 0; n < 4; n++) { acc1[m][n] = f32x4{0.f,0.f,0.f,0.f}; acc3[m][n] = f32x4{0.f,0.f,0.f,0.f}; }

  // one 16B chunk per thread per buffer: chunk index = tid, row = tid>>2, k-chunk = tid&3
  int arow = tid >> 2, koff = (tid & 3) * 8;
  const unsigned short* ga  = xbf + (size_t)gtok[row0 + arow] * DIM + koff;   // per-lane gather
  const unsigned short* gb1 = B1 + (size_t)(col0 + arow) * DIM + koff;
  const unsigned short* gb3 = B3 + (size_t)(col0 + arow) * DIM + koff;
  unsigned short* lA  = As  + wave * 512;   // wave-uniform base; HW adds lane*16B
  unsigned short* lB1 = Bs1 + wave * 512;
  unsigned short* lB3 = Bs3 + wave * 512;

  int kc = lane >> 4, rl = lane & 15;

  for (int k0 = 0; k0 < DIM; k0 += 32) {
    gload_lds16(ga + k0, lA);
    gload_lds16(gb1 + k0, lB1);
    gload_lds16(gb3 + k0, lB3);
    __syncthreads();   // drains vmcnt before use

    const bf16x8* Ap  = (const bf16x8*)As;
    const bf16x8* B1p = (const bf16x8*)Bs1;
    const bf16x8* B3p = (const bf16x8*)Bs3;
    bf16x8 af[2], b1f[4], b3f[4];
#pragma unroll
    for (int m = 0; m < 2; m++) af[m] = Ap[(wrow + m * 16 + rl) * 4 + kc];
#pragma unroll
    for (int n = 0; n < 4; n++) { b1f[n] = B1p[(wcol + n * 16 + rl) * 4 + kc];
                                  b3f[n] = B3p[(wcol + n * 16 + rl) * 4 + kc]; }
#pragma unroll
    for (int m = 0; m < 2; m++)
#pragma unroll
      for (int n = 0; n < 4; n++) {
        acc1[m][n] = __builtin_amdgcn_mfma_f32_16x16x32_bf16(af[m], b1f[n], acc1[m][n], 0, 0, 0);
        acc3[m][n] = __builtin_amdgcn_mfma_f32_16x16x32_bf16(af[m], b3f[n], acc3[m][n], 0, 0, 0);
      }
    __syncthreads();   // before next stage overwrites LDS
  }

  int rj = lane >> 4, cl = lane & 15;
#pragma unroll
  for (int m = 0; m < 2; m++)
#pragma unroll
    for (int n = 0; n < 4; n++)
#pragma unroll
      for (int j = 0; j < 4; j++) {
        int lr = wrow + m * 16 + rj * 4 + j;
        float s = ss[lr];
        float a = s * acc1[m][n][j];
        float g = s * acc3[m][n][j];
        float si = a / (1.f + __expf(-a));
        H[(size_t)(row0 + lr) * DIM + (col0 + wcol + n * 16 + cl)] = f2bf(si * g);
      }
}

// ---------------- grouped GEMM: rout = H * W2_e (fp32 out); 512 threads ------------------------
__global__ __launch_bounds__(512, 4) void gemm2(
    const unsigned short* __restrict__ A, const unsigned short* __restrict__ W,
    const unsigned short* __restrict__ Wsh, float* __restrict__ C,
    const int* __restrict__ tile_e, const int* __restrict__ tile_r0,
    const int* __restrict__ ntiles) {
  if ((int)blockIdx.y >= *ntiles) return;
  int e = tile_e[blockIdx.y];
  int row0 = tile_r0[blockIdx.y];
  int col0 = blockIdx.x * 128;
  const unsigned short* B = (e < NEXP) ? (W + (size_t)e * MM) : Wsh;

  __shared__ __align__(16) unsigned short As[128 * 32];
  __shared__ __align__(16) unsigned short Bs[128 * 32];

  int tid = threadIdx.x;
  int wave = tid >> 6, lane = tid & 63;
  int wrow = (wave & 3) * 32, wcol = (wave >> 2) * 64;

  f32x4 acc[2][4];
#pragma unroll
  for (int m = 0; m < 2; m++)
#pragma unroll
    for (int n = 0; n < 4; n++) acc[m][n] = f32x4{0.f, 0.f, 0.f, 0.f};

  int arow = tid >> 2, koff = (tid & 3) * 8;
  const unsigned short* ga = A + (size_t)(row0 + arow) * DIM + koff;
  const unsigned short* gb = B + (size_t)(col0 + arow) * DIM + koff;
  unsigned short* lA = As + wave * 512;
  unsigned short* lB = Bs + wave * 512;

  int kc = lane >> 4, rl = lane & 15;

  for (int k0 = 0; k0 < DIM; k0 += 32) {
    gload_lds16(ga + k0, lA);
    gload_lds16(gb + k0, lB);
    __syncthreads();

    const bf16x8* Ap = (const bf16x8*)As;
    const bf16x8* Bp = (const bf16x8*)Bs;
    bf16x8 af[2], bfr[4];
#pragma unroll
    for (int m = 0; m < 2; m++) af[m] = Ap[(wrow + m * 16 + rl) * 4 + kc];
#pragma unroll
    for (int n = 0; n < 4; n++) bfr[n] = Bp[(wcol + n * 16 + rl) * 4 + kc];
#pragma unroll
    for (int m = 0; m < 2; m++)
#pragma unroll
      for (int n = 0; n < 4; n++)
        acc[m][n] = __builtin_amdgcn_mfma_f32_16x16x32_bf16(af[m], bfr[n], acc[m][n], 0, 0, 0);
    __syncthreads();
  }

  int rj = lane >> 4, cl = lane & 15;
#pragma unroll
  for (int m = 0; m < 2; m++)
#pragma unroll
    for (int n = 0; n < 4; n++)
#pragma unroll
      for (int j = 0; j < 4; j++) {
        int r = row0 + wrow + m * 16 + rj * 4 + j;
        int c = col0 + wcol + n * 16 + cl;
        C[(size_t)r * DIM + c] = acc[m][n][j];
      }
}

// ---------------- combine: out[t] = rout[r0] + rout[r1] + rout[shared] -------------------------
__global__ __launch_bounds__(256) void combine(const float* __restrict__ rout,
                                               const int* __restrict__ row_of,
                                               const int* __restrict__ base8,
                                               float* __restrict__ out) {
  int t = blockIdx.x;
  int c = threadIdx.x * 4;
  int r0 = row_of[2 * t], r1 = row_of[2 * t + 1];
  int rs = *base8 + t;
  float4 v0 = *(const float4*)(rout + (size_t)r0 * DIM + c);
  float4 v1 = *(const float4*)(rout + (size_t)r1 * DIM + c);
  float4 v2 = *(const float4*)(rout + (size_t)rs * DIM + c);
  float4 o;
  o.x = v0.x + v1.x + v2.x;
  o.y = v0.y + v1.y + v2.y;
  o.z = v0.z + v1.z + v2.z;
  o.w = v0.w + v1.w + v2.w;
  *(float4*)(out + (size_t)t * DIM + c) = o;
}

extern "C" void kernel_launch(void* const* d_in, const int* in_sizes, int n_in,
                              void* d_out, int out_size, void* d_ws, size_t ws_size,
                              hipStream_t stream) {
  const float* x   = (const float*)d_in[0];
  const float* gw  = (const float*)d_in[1];
  const float* w1  = (const float*)d_in[2];
  const float* w2  = (const float*)d_in[3];
  const float* w3  = (const float*)d_in[4];
  const float* w1s = (const float*)d_in[5];
  const float* w2s = (const float*)d_in[6];
  const float* w3s = (const float*)d_in[7];
  float* out = (float*)d_out;
  char* ws = (char*)d_ws;

  const size_t MB = 1ull << 20;
  unsigned short* w1t  = (unsigned short*)(ws + 0 * MB);    // 16MB [8][1024][1024] B^T bf16
  unsigned short* w3t  = (unsigned short*)(ws + 16 * MB);   // 16MB
  unsigned short* w2t  = (unsigned short*)(ws + 32 * MB);   // 16MB
  unsigned short* w1st = (unsigned short*)(ws + 48 * MB);   // 2MB
  unsigned short* w3st = (unsigned short*)(ws + 50 * MB);   // 2MB
  unsigned short* w2st = (unsigned short*)(ws + 52 * MB);   // 2MB
  unsigned short* xbf  = (unsigned short*)(ws + 54 * MB);   // 4MB+  [NTOK+1][1024] bf16
  unsigned short* hbuf = (unsigned short*)(ws + 60 * MB);   // 16MB [8192][1024] bf16
  float* rout = (float*)(ws + 76 * MB);                     // 32MB [8192][1024] fp32
  char* meta = ws + 108 * MB;
  int*   e0p    = (int*)meta;
  int*   e1p    = e0p + NTOK;
  float* s0p    = (float*)(e1p + NTOK);
  float* s1p    = s0p + NTOK;
  int*   gtok   = (int*)(s1p + NTOK);
  float* gsc    = (float*)(gtok + ROWS_CAP);
  int*   row_of = (int*)(gsc + ROWS_CAP);
  int*   tile_e = row_of + NENT;
  int*   tile_r0= tile_e + MAX_TILES;
  int*   ntiles = tile_r0 + MAX_TILES;
  int*   base8  = ntiles + 1;

  cast_x<<<NTOK + 1, 256, 0, stream>>>(x, xbf);
  router<<<NTOK, 64, 0, stream>>>(x, gw, e0p, e1p, s0p, s1p);
  build_groups<<<1, 256, 0, stream>>>(e0p, e1p, s0p, s1p, gtok, gsc, row_of,
                                      tile_e, tile_r0, ntiles, base8);
  transpose_all<<<dim3(64, 1, 27), 256, 0, stream>>>(
      w1, w3, w2, w1s, w3s, w2s, w1t, w3t, w2t, w1st, w3st, w2st);

  dim3 gg(8, MAX_TILES);
  gemm13<<<gg, 512, 0, stream>>>(xbf, w1t, w1st, w3t, w3st, hbuf,
                                 gtok, gsc, tile_e, tile_r0, ntiles);
  gemm2<<<gg, 512, 0, stream>>>(hbuf, w2t, w2st, rout, tile_e, tile_r0, ntiles);

  combine<<<NTOK, 256, 0, stream>>>(rout, row_of, base8, out);
}

// Round 9
// 125.594 us; speedup vs baseline: 1.1546x; 1.1546x over previous
//
#include <hip/hip_runtime.h>
#include <hip/hip_bf16.h>

// MoE top-2 + shared expert, bf16 MFMA path. Round 9.
// vs R7 (125.9us best): transpose_all keeps R7's LDS staging + proven global
// patterns but does a 4x4 register micro-transpose so LDS writes are 8x
// ds_write_b64 per thread instead of 32x scalar ds_write_b16 (R7's cost).
// R8's register-only version regressed (16B stores @2KB stride -> partial-line
// RMW, WRITE_SIZE 55->78MB). GEMMs unchanged (512thr/8wave, R7-winning form).

#define DIM 1024
#define NTOK 2048
#define NEXP 8
#define NENT 4096          // NTOK * 2
#define ROWS_CAP 8192      // padded grouped rows upper bound
#define MAX_TILES 64
#define MM (DIM * DIM)

typedef float f32x4 __attribute__((ext_vector_type(4)));
typedef __bf16 bf16x8 __attribute__((ext_vector_type(8)));

__device__ __forceinline__ unsigned short f2bf(float f) {
  unsigned int u = __builtin_bit_cast(unsigned int, f);
  unsigned int r = u + 0x7FFFu + ((u >> 16) & 1u);   // RNE
  return (unsigned short)(r >> 16);
}
__device__ __forceinline__ void gload_lds16(const unsigned short* g, unsigned short* l) {
  __builtin_amdgcn_global_load_lds((__attribute__((address_space(1))) const void*)g,
                                   (__attribute__((address_space(3))) void*)l, 16, 0, 0);
}

// ---------------- x -> bf16 (row NTOK is an all-zero pad row) ----------------------------------
__global__ __launch_bounds__(256) void cast_x(const float* __restrict__ x,
                                              unsigned short* __restrict__ xbf) {
  int r = blockIdx.x;                 // 0..NTOK
  int c = threadIdx.x * 4;
  ushort4 o;
  if (r < NTOK) {
    float4 v = *(const float4*)(x + (size_t)r * DIM + c);
    o.x = f2bf(v.x); o.y = f2bf(v.y); o.z = f2bf(v.z); o.w = f2bf(v.w);
  } else {
    o.x = o.y = o.z = o.w = 0;
  }
  *(ushort4*)(xbf + (size_t)r * DIM + c) = o;
}

// ---------------- weight transpose+cast: dst[n][k] = bf16(src[k][n]), 27 z-slices --------------
// Tile 32n x 256k per block. Phase 1: each thread takes two 4x4 micro-blocks,
// register-transposes, writes columns as ds_write_b64 (4 bf16). Row stride
// 528B (pad 8 bf16) -> write banks = b64 wave-minimum. Phase 2 (= R4/R7):
// b128 LDS reads, 512B-contiguous uint4 global stores.
__global__ __launch_bounds__(256) void transpose_all(
    const float* __restrict__ w1, const float* __restrict__ w3, const float* __restrict__ w2,
    const float* __restrict__ w1s, const float* __restrict__ w3s, const float* __restrict__ w2s,
    unsigned short* __restrict__ w1t, unsigned short* __restrict__ w3t,
    unsigned short* __restrict__ w2t, unsigned short* __restrict__ w1st,
    unsigned short* __restrict__ w3st, unsigned short* __restrict__ w2st) {
  __shared__ __align__(16) char lds[32 * 528];   // [n][264 bf16], stride 528B
  int z = blockIdx.z;
  const float* src; unsigned short* dst;
  if (z < 8)       { src = w1 + (size_t)z * MM;        dst = w1t + (size_t)z * MM; }
  else if (z < 16) { src = w3 + (size_t)(z - 8) * MM;  dst = w3t + (size_t)(z - 8) * MM; }
  else if (z < 24) { src = w2 + (size_t)(z - 16) * MM; dst = w2t + (size_t)(z - 16) * MM; }
  else if (z == 24){ src = w1s; dst = w1st; }
  else if (z == 25){ src = w3s; dst = w3st; }
  else             { src = w2s; dst = w2st; }
  int r0 = blockIdx.y * 256, c0 = blockIdx.x * 32;
  int tid = threadIdx.x;
  int q = tid & 7;                    // n-quad 0..7 (n = 4q..4q+3)
#pragma unroll
  for (int mb = 0; mb < 2; mb++) {
    int kq = (tid >> 3) + mb * 32;    // k-quad 0..63 (k = 4kq..4kq+3)
    const float* sp = src + (size_t)(r0 + kq * 4) * DIM + c0 + q * 4;
    float4 v0 = *(const float4*)(sp + 0 * DIM);
    float4 v1 = *(const float4*)(sp + 1 * DIM);
    float4 v2 = *(const float4*)(sp + 2 * DIM);
    float4 v3 = *(const float4*)(sp + 3 * DIM);
    float a0[4] = {v0.x, v0.y, v0.z, v0.w};
    float a1[4] = {v1.x, v1.y, v1.z, v1.w};
    float a2[4] = {v2.x, v2.y, v2.z, v2.w};
    float a3[4] = {v3.x, v3.y, v3.z, v3.w};
#pragma unroll
    for (int j = 0; j < 4; j++) {     // output row n = 4q+j gets column j
      uint2 p;
      p.x = f2bf(a0[j]) | ((unsigned int)f2bf(a1[j]) << 16);
      p.y = f2bf(a2[j]) | ((unsigned int)f2bf(a3[j]) << 16);
      *(uint2*)(lds + (q * 4 + j) * 528 + kq * 8) = p;
    }
  }
  __syncthreads();
  int c = tid >> 5;                   // row 0..7 (+8i)
  int ch = tid & 31;                  // 16B chunk 0..31
#pragma unroll
  for (int i = 0; i < 4; i++) {
    int row = c + i * 8;
    uint4 val = *(const uint4*)(lds + row * 528 + ch * 16);
    *(uint4*)(dst + (size_t)(c0 + row) * DIM + r0 + ch * 8) = val;
  }
}

// ---------------- router: fp32 logits -> softmax -> top-2 --------------------------------------
__global__ __launch_bounds__(64) void router(const float* __restrict__ x,
                                             const float* __restrict__ gw,
                                             int* __restrict__ e0, int* __restrict__ e1,
                                             float* __restrict__ s0, float* __restrict__ s1) {
  int t = blockIdx.x;
  int lane = threadIdx.x;
  const float* xr = x + (size_t)t * DIM;
  float acc[NEXP];
#pragma unroll
  for (int e = 0; e < NEXP; e++) acc[e] = 0.f;
  for (int i = 0; i < DIM / 64; i++) {
    float xv = xr[i * 64 + lane];
#pragma unroll
    for (int e = 0; e < NEXP; e++) acc[e] += xv * gw[e * DIM + i * 64 + lane];
  }
#pragma unroll
  for (int e = 0; e < NEXP; e++) {
    float v = acc[e];
    for (int o = 32; o > 0; o >>= 1) v += __shfl_xor(v, o);
    acc[e] = v;
  }
  if (lane == 0) {
    float m = acc[0];
#pragma unroll
    for (int e = 1; e < NEXP; e++) m = fmaxf(m, acc[e]);
    float ex[NEXP]; float Z = 0.f;
#pragma unroll
    for (int e = 0; e < NEXP; e++) { ex[e] = __expf(acc[e] - m); Z += ex[e]; }
    float inv = 1.f / Z;
    float sc[NEXP];
#pragma unroll
    for (int e = 0; e < NEXP; e++) sc[e] = ex[e] * inv;
    int b0 = 0; float v0 = sc[0];
#pragma unroll
    for (int e = 1; e < NEXP; e++) if (sc[e] > v0) { v0 = sc[e]; b0 = e; }
    int b1 = -1; float v1 = -1.f;
#pragma unroll
    for (int e = 0; e < NEXP; e++) if (e != b0 && sc[e] > v1) { v1 = sc[e]; b1 = e; }
    e0[t] = b0; e1[t] = b1; s0[t] = v0; s1[t] = v1;
  }
}

// ---------------- deterministic grouped build: packed uint4 scan (128-row padding) -------------
__global__ __launch_bounds__(256) void build_groups(
    const int* __restrict__ e0, const int* __restrict__ e1,
    const float* __restrict__ s0, const float* __restrict__ s1,
    int* __restrict__ gtok, float* __restrict__ gsc, int* __restrict__ row_of,
    int* __restrict__ tile_e, int* __restrict__ tile_r0, int* __restrict__ ntiles,
    int* __restrict__ base8out) {
  __shared__ unsigned int wsum[4][4];
  __shared__ int offl[256][NEXP];
  __shared__ int lrl[256][NEXP];
  int t = threadIdx.x, lane = t & 63, wave = t >> 6;

  for (int i = t; i < ROWS_CAP; i += 256) { gtok[i] = NTOK; gsc[i] = 0.f; }  // pad -> zero row

  unsigned int pc[4] = {0, 0, 0, 0};
#pragma unroll
  for (int i = 0; i < 16; i++) {
    int ent = t * 16 + i;
    int tok = ent >> 1;
    int e = (ent & 1) ? e1[tok] : e0[tok];
    unsigned int add = 1u << ((e & 1) * 16);
    int c = e >> 1;
    if (c == 0) pc[0] += add; else if (c == 1) pc[1] += add;
    else if (c == 2) pc[2] += add; else pc[3] += add;
  }
  unsigned int incl[4] = {pc[0], pc[1], pc[2], pc[3]};
#pragma unroll
  for (int o = 1; o < 64; o <<= 1) {
    unsigned int u0 = __shfl_up(incl[0], o), u1 = __shfl_up(incl[1], o);
    unsigned int u2 = __shfl_up(incl[2], o), u3 = __shfl_up(incl[3], o);
    if (lane >= o) { incl[0] += u0; incl[1] += u1; incl[2] += u2; incl[3] += u3; }
  }
  if (lane == 63) { wsum[wave][0] = incl[0]; wsum[wave][1] = incl[1];
                    wsum[wave][2] = incl[2]; wsum[wave][3] = incl[3]; }
  __syncthreads();
  unsigned int T[4], pre[4] = {0, 0, 0, 0};
#pragma unroll
  for (int c = 0; c < 4; c++)
    T[c] = wsum[0][c] + wsum[1][c] + wsum[2][c] + wsum[3][c];
#pragma unroll
  for (int w = 0; w < 3; w++)
    if (wave > w) { pre[0] += wsum[w][0]; pre[1] += wsum[w][1];
                    pre[2] += wsum[w][2]; pre[3] += wsum[w][3]; }
  int base[NEXP + 1];
  {
    int b = 0;
#pragma unroll
    for (int e = 0; e < NEXP; e++) {
      int tot = (int)((T[e >> 1] >> ((e & 1) * 16)) & 0xFFFFu);
      base[e] = b; b += (tot + 127) & ~127;
    }
    base[NEXP] = b;
  }
#pragma unroll
  for (int e = 0; e < NEXP; e++) {
    unsigned int ex = (incl[e >> 1] + pre[e >> 1] - pc[e >> 1]);
    offl[t][e] = (int)((ex >> ((e & 1) * 16)) & 0xFFFFu);
    lrl[t][e] = 0;
  }
  if (t == 0) {
    int nt = 0;
#pragma unroll
    for (int e = 0; e < NEXP; e++) {
      int tot = (int)((T[e >> 1] >> ((e & 1) * 16)) & 0xFFFFu);
      int ntl = (tot + 127) >> 7;
      for (int i = 0; i < ntl; i++) { tile_e[nt] = e; tile_r0[nt] = base[e] + i * 128; nt++; }
    }
    for (int i = 0; i < NTOK / 128; i++) { tile_e[nt] = NEXP; tile_r0[nt] = base[NEXP] + i * 128; nt++; }
    *ntiles = nt;
    *base8out = base[NEXP];
  }
  __syncthreads();   // gtok/gsc clear complete before scatter

#pragma unroll
  for (int i = 0; i < 16; i++) {
    int ent = t * 16 + i;
    int tok = ent >> 1;
    int k = ent & 1;
    int e = k ? e1[tok] : e0[tok];
    float s = k ? s1[tok] : s0[tok];
    int pos = base[e] + offl[t][e] + lrl[t][e];
    lrl[t][e]++;
    gtok[pos] = tok; gsc[pos] = s; row_of[ent] = pos;
  }
  for (int i = t; i < NTOK; i += 256) { gtok[base[NEXP] + i] = i; gsc[base[NEXP] + i] = 1.0f; }
}

// ------- fused grouped GEMM: h = silu(s*(A*W1_e)) * (s*(A*W3_e)), A gathered from xbf ----------
// 512 threads / 8 waves on a 128x128 tile; wave-tile 32x64; 3 gloads/thread/step.
__global__ __launch_bounds__(512, 4) void gemm13(
    const unsigned short* __restrict__ xbf,
    const unsigned short* __restrict__ W1, const unsigned short* __restrict__ W1s,
    const unsigned short* __restrict__ W3, const unsigned short* __restrict__ W3s,
    unsigned short* __restrict__ H,
    const int* __restrict__ gtok, const float* __restrict__ gsc,
    const int* __restrict__ tile_e, const int* __restrict__ tile_r0,
    const int* __restrict__ ntiles) {
  if ((int)blockIdx.y >= *ntiles) return;
  int e = tile_e[blockIdx.y];
  int row0 = tile_r0[blockIdx.y];
  int col0 = blockIdx.x * 128;
  const unsigned short* B1 = (e < NEXP) ? (W1 + (size_t)e * MM) : W1s;
  const unsigned short* B3 = (e < NEXP) ? (W3 + (size_t)e * MM) : W3s;

  __shared__ __align__(16) unsigned short As[128 * 32];    // 8KB
  __shared__ __align__(16) unsigned short Bs1[128 * 32];   // 8KB
  __shared__ __align__(16) unsigned short Bs3[128 * 32];   // 8KB
  __shared__ float ss[128];

  int tid = threadIdx.x;
  int wave = tid >> 6, lane = tid & 63;
  int wrow = (wave & 3) * 32, wcol = (wave >> 2) * 64;

  if (tid < 128) ss[tid] = gsc[row0 + tid];   // synced by first K-loop barrier

  f32x4 acc1[2][4], acc3[2][4];
#pragma unroll
  for (int m = 0; m < 2; m++)
#pragma unroll
    for (int n = 0; n < 4; n++) { acc1[m][n] = f32x4{0.f,0.f,0.f,0.f}; acc3[m][n] = f32x4{0.f,0.f,0.f,0.f}; }

  // one 16B chunk per thread per buffer: chunk index = tid, row = tid>>2, k-chunk = tid&3
  int arow = tid >> 2, koff = (tid & 3) * 8;
  const unsigned short* ga  = xbf + (size_t)gtok[row0 + arow] * DIM + koff;   // per-lane gather
  const unsigned short* gb1 = B1 + (size_t)(col0 + arow) * DIM + koff;
  const unsigned short* gb3 = B3 + (size_t)(col0 + arow) * DIM + koff;
  unsigned short* lA  = As  + wave * 512;   // wave-uniform base; HW adds lane*16B
  unsigned short* lB1 = Bs1 + wave * 512;
  unsigned short* lB3 = Bs3 + wave * 512;

  int kc = lane >> 4, rl = lane & 15;

  for (int k0 = 0; k0 < DIM; k0 += 32) {
    gload_lds16(ga + k0, lA);
    gload_lds16(gb1 + k0, lB1);
    gload_lds16(gb3 + k0, lB3);
    __syncthreads();   // drains vmcnt before use

    const bf16x8* Ap  = (const bf16x8*)As;
    const bf16x8* B1p = (const bf16x8*)Bs1;
    const bf16x8* B3p = (const bf16x8*)Bs3;
    bf16x8 af[2], b1f[4], b3f[4];
#pragma unroll
    for (int m = 0; m < 2; m++) af[m] = Ap[(wrow + m * 16 + rl) * 4 + kc];
#pragma unroll
    for (int n = 0; n < 4; n++) { b1f[n] = B1p[(wcol + n * 16 + rl) * 4 + kc];
                                  b3f[n] = B3p[(wcol + n * 16 + rl) * 4 + kc]; }
#pragma unroll
    for (int m = 0; m < 2; m++)
#pragma unroll
      for (int n = 0; n < 4; n++) {
        acc1[m][n] = __builtin_amdgcn_mfma_f32_16x16x32_bf16(af[m], b1f[n], acc1[m][n], 0, 0, 0);
        acc3[m][n] = __builtin_amdgcn_mfma_f32_16x16x32_bf16(af[m], b3f[n], acc3[m][n], 0, 0, 0);
      }
    __syncthreads();   // before next stage overwrites LDS
  }

  int rj = lane >> 4, cl = lane & 15;
#pragma unroll
  for (int m = 0; m < 2; m++)
#pragma unroll
    for (int n = 0; n < 4; n++)
#pragma unroll
      for (int j = 0; j < 4; j++) {
        int lr = wrow + m * 16 + rj * 4 + j;
        float s = ss[lr];
        float a = s * acc1[m][n][j];
        float g = s * acc3[m][n][j];
        float si = a / (1.f + __expf(-a));
        H[(size_t)(row0 + lr) * DIM + (col0 + wcol + n * 16 + cl)] = f2bf(si * g);
      }
}

// ---------------- grouped GEMM: rout = H * W2_e (fp32 out); 512 threads ------------------------
__global__ __launch_bounds__(512, 4) void gemm2(
    const unsigned short* __restrict__ A, const unsigned short* __restrict__ W,
    const unsigned short* __restrict__ Wsh, float* __restrict__ C,
    const int* __restrict__ tile_e, const int* __restrict__ tile_r0,
    const int* __restrict__ ntiles) {
  if ((int)blockIdx.y >= *ntiles) return;
  int e = tile_e[blockIdx.y];
  int row0 = tile_r0[blockIdx.y];
  int col0 = blockIdx.x * 128;
  const unsigned short* B = (e < NEXP) ? (W + (size_t)e * MM) : Wsh;

  __shared__ __align__(16) unsigned short As[128 * 32];
  __shared__ __align__(16) unsigned short Bs[128 * 32];

  int tid = threadIdx.x;
  int wave = tid >> 6, lane = tid & 63;
  int wrow = (wave & 3) * 32, wcol = (wave >> 2) * 64;

  f32x4 acc[2][4];
#pragma unroll
  for (int m = 0; m < 2; m++)
#pragma unroll
    for (int n = 0; n < 4; n++) acc[m][n] = f32x4{0.f, 0.f, 0.f, 0.f};

  int arow = tid >> 2, koff = (tid & 3) * 8;
  const unsigned short* ga = A + (size_t)(row0 + arow) * DIM + koff;
  const unsigned short* gb = B + (size_t)(col0 + arow) * DIM + koff;
  unsigned short* lA = As + wave * 512;
  unsigned short* lB = Bs + wave * 512;

  int kc = lane >> 4, rl = lane & 15;

  for (int k0 = 0; k0 < DIM; k0 += 32) {
    gload_lds16(ga + k0, lA);
    gload_lds16(gb + k0, lB);
    __syncthreads();

    const bf16x8* Ap = (const bf16x8*)As;
    const bf16x8* Bp = (const bf16x8*)Bs;
    bf16x8 af[2], bfr[4];
#pragma unroll
    for (int m = 0; m < 2; m++) af[m] = Ap[(wrow + m * 16 + rl) * 4 + kc];
#pragma unroll
    for (int n = 0; n < 4; n++) bfr[n] = Bp[(wcol + n * 16 + rl) * 4 + kc];
#pragma unroll
    for (int m = 0; m < 2; m++)
#pragma unroll
      for (int n = 0; n < 4; n++)
        acc[m][n] = __builtin_amdgcn_mfma_f32_16x16x32_bf16(af[m], bfr[n], acc[m][n], 0, 0, 0);
    __syncthreads();
  }

  int rj = lane >> 4, cl = lane & 15;
#pragma unroll
  for (int m = 0; m < 2; m++)
#pragma unroll
    for (int n = 0; n < 4; n++)
#pragma unroll
      for (int j = 0; j < 4; j++) {
        int r = row0 + wrow + m * 16 + rj * 4 + j;
        int c = col0 + wcol + n * 16 + cl;
        C[(size_t)r * DIM + c] = acc[m][n][j];
      }
}

// ---------------- combine: out[t] = rout[r0] + rout[r1] + rout[shared] -------------------------
__global__ __launch_bounds__(256) void combine(const float* __restrict__ rout,
                                               const int* __restrict__ row_of,
                                               const int* __restrict__ base8,
                                               float* __restrict__ out) {
  int t = blockIdx.x;
  int c = threadIdx.x * 4;
  int r0 = row_of[2 * t], r1 = row_of[2 * t + 1];
  int rs = *base8 + t;
  float4 v0 = *(const float4*)(rout + (size_t)r0 * DIM + c);
  float4 v1 = *(const float4*)(rout + (size_t)r1 * DIM + c);
  float4 v2 = *(const float4*)(rout + (size_t)rs * DIM + c);
  float4 o;
  o.x = v0.x + v1.x + v2.x;
  o.y = v0.y + v1.y + v2.y;
  o.z = v0.z + v1.z + v2.z;
  o.w = v0.w + v1.w + v2.w;
  *(float4*)(out + (size_t)t * DIM + c) = o;
}

extern "C" void kernel_launch(void* const* d_in, const int* in_sizes, int n_in,
                              void* d_out, int out_size, void* d_ws, size_t ws_size,
                              hipStream_t stream) {
  const float* x   = (const float*)d_in[0];
  const float* gw  = (const float*)d_in[1];
  const float* w1  = (const float*)d_in[2];
  const float* w2  = (const float*)d_in[3];
  const float* w3  = (const float*)d_in[4];
  const float* w1s = (const float*)d_in[5];
  const float* w2s = (const float*)d_in[6];
  const float* w3s = (const float*)d_in[7];
  float* out = (float*)d_out;
  char* ws = (char*)d_ws;

  const size_t MB = 1ull << 20;
  unsigned short* w1t  = (unsigned short*)(ws + 0 * MB);    // 16MB [8][1024][1024] B^T bf16
  unsigned short* w3t  = (unsigned short*)(ws + 16 * MB);   // 16MB
  unsigned short* w2t  = (unsigned short*)(ws + 32 * MB);   // 16MB
  unsigned short* w1st = (unsigned short*)(ws + 48 * MB);   // 2MB
  unsigned short* w3st = (unsigned short*)(ws + 50 * MB);   // 2MB
  unsigned short* w2st = (unsigned short*)(ws + 52 * MB);   // 2MB
  unsigned short* xbf  = (unsigned short*)(ws + 54 * MB);   // 4MB+  [NTOK+1][1024] bf16
  unsigned short* hbuf = (unsigned short*)(ws + 60 * MB);   // 16MB [8192][1024] bf16
  float* rout = (float*)(ws + 76 * MB);                     // 32MB [8192][1024] fp32
  char* meta = ws + 108 * MB;
  int*   e0p    = (int*)meta;
  int*   e1p    = e0p + NTOK;
  float* s0p    = (float*)(e1p + NTOK);
  float* s1p    = s0p + NTOK;
  int*   gtok   = (int*)(s1p + NTOK);
  float* gsc    = (float*)(gtok + ROWS_CAP);
  int*   row_of = (int*)(gsc + ROWS_CAP);
  int*   tile_e = row_of + NENT;
  int*   tile_r0= tile_e + MAX_TILES;
  int*   ntiles = tile_r0 + MAX_TILES;
  int*   base8  = ntiles + 1;

  cast_x<<<NTOK + 1, 256, 0, stream>>>(x, xbf);
  router<<<NTOK, 64, 0, stream>>>(x, gw, e0p, e1p, s0p, s1p);
  build_groups<<<1, 256, 0, stream>>>(e0p, e1p, s0p, s1p, gtok, gsc, row_of,
                                      tile_e, tile_r0, ntiles, base8);
  transpose_all<<<dim3(32, 4, 27), 256, 0, stream>>>(
      w1, w3, w2, w1s, w3s, w2s, w1t, w3t, w2t, w1st, w3st, w2st);

  dim3 gg(8, MAX_TILES);
  gemm13<<<gg, 512, 0, stream>>>(xbf, w1t, w1st, w3t, w3st, hbuf,
                                 gtok, gsc, tile_e, tile_r0, ntiles);
  gemm2<<<gg, 512, 0, stream>>>(hbuf, w2t, w2st, rout, tile_e, tile_r0, ntiles);

  combine<<<NTOK, 256, 0, stream>>>(rout, row_of, base8, out);
}

// Round 10
// 122.124 us; speedup vs baseline: 1.1874x; 1.0284x over previous
//
#include <hip/hip_runtime.h>
#include <hip/hip_bf16.h>

// MoE top-2 + shared expert, bf16 MFMA path. Round 10.
// vs R9 (125.6us): (1) transpose_all v3 — 512-thr blocks, 64n x 256k tile,
// ALL 8 float4 loads issued before packing (R9's VGPR=28 forced 2 serialized
// load rounds -> 0.9us wave lifetime x 54 slots/CU = the measured 49us);
// (2) cast_x fused into router (x read once, pad row written by block 0).
// GEMMs/build/combine identical to the R7/R9 winning forms. No atomics.

#define DIM 1024
#define NTOK 2048
#define NEXP 8
#define NENT 4096          // NTOK * 2
#define ROWS_CAP 8192      // padded grouped rows upper bound
#define MAX_TILES 64
#define MM (DIM * DIM)

typedef float f32x4 __attribute__((ext_vector_type(4)));
typedef __bf16 bf16x8 __attribute__((ext_vector_type(8)));

__device__ __forceinline__ unsigned short f2bf(float f) {
  unsigned int u = __builtin_bit_cast(unsigned int, f);
  unsigned int r = u + 0x7FFFu + ((u >> 16) & 1u);   // RNE
  return (unsigned short)(r >> 16);
}
__device__ __forceinline__ void gload_lds16(const unsigned short* g, unsigned short* l) {
  __builtin_amdgcn_global_load_lds((__attribute__((address_space(1))) const void*)g,
                                   (__attribute__((address_space(3))) void*)l, 16, 0, 0);
}

// ---------------- weight transpose+cast v3: dst[n][k] = bf16(src[k][n]), 27 z-slices -----------
// 512 threads, tile 64n x 256k. Phase 1: 8 float4 loads ALL in flight, 4x4
// register micro-transpose x2, 8x ds_write_b64 (528B row stride). Phase 2:
// b128 LDS reads, 2x512B-contiguous uint4 global stores per instr.
__global__ __launch_bounds__(512) void transpose_all(
    const float* __restrict__ w1, const float* __restrict__ w3, const float* __restrict__ w2,
    const float* __restrict__ w1s, const float* __restrict__ w3s, const float* __restrict__ w2s,
    unsigned short* __restrict__ w1t, unsigned short* __restrict__ w3t,
    unsigned short* __restrict__ w2t, unsigned short* __restrict__ w1st,
    unsigned short* __restrict__ w3st, unsigned short* __restrict__ w2st) {
  __shared__ __align__(16) char lds[64 * 528];   // [n][264 bf16]
  int z = blockIdx.z;
  const float* src; unsigned short* dst;
  if (z < 8)       { src = w1 + (size_t)z * MM;        dst = w1t + (size_t)z * MM; }
  else if (z < 16) { src = w3 + (size_t)(z - 8) * MM;  dst = w3t + (size_t)(z - 8) * MM; }
  else if (z < 24) { src = w2 + (size_t)(z - 16) * MM; dst = w2t + (size_t)(z - 16) * MM; }
  else if (z == 24){ src = w1s; dst = w1st; }
  else if (z == 25){ src = w3s; dst = w3st; }
  else             { src = w2s; dst = w2st; }
  int r0 = blockIdx.y * 256, c0 = blockIdx.x * 64;
  int tid = threadIdx.x;
  int q = tid & 15;                   // n-quad 0..15 (n = 4q..4q+3)
  int kq = tid >> 4;                  // k-quad 0..31; second micro-block at kq+32

  const float* sp0 = src + (size_t)(r0 + kq * 4) * DIM + c0 + q * 4;
  const float* sp1 = sp0 + (size_t)128 * DIM;   // k-quads 32..63
  // all 8 loads issued before any dependent use
  float4 v0 = *(const float4*)(sp0 + 0 * DIM);
  float4 v1 = *(const float4*)(sp0 + 1 * DIM);
  float4 v2 = *(const float4*)(sp0 + 2 * DIM);
  float4 v3 = *(const float4*)(sp0 + 3 * DIM);
  float4 v4 = *(const float4*)(sp1 + 0 * DIM);
  float4 v5 = *(const float4*)(sp1 + 1 * DIM);
  float4 v6 = *(const float4*)(sp1 + 2 * DIM);
  float4 v7 = *(const float4*)(sp1 + 3 * DIM);
  float a0[4] = {v0.x, v0.y, v0.z, v0.w};
  float a1[4] = {v1.x, v1.y, v1.z, v1.w};
  float a2[4] = {v2.x, v2.y, v2.z, v2.w};
  float a3[4] = {v3.x, v3.y, v3.z, v3.w};
  float b0[4] = {v4.x, v4.y, v4.z, v4.w};
  float b1[4] = {v5.x, v5.y, v5.z, v5.w};
  float b2[4] = {v6.x, v6.y, v6.z, v6.w};
  float b3[4] = {v7.x, v7.y, v7.z, v7.w};
#pragma unroll
  for (int j = 0; j < 4; j++) {
    uint2 p;
    p.x = f2bf(a0[j]) | ((unsigned int)f2bf(a1[j]) << 16);
    p.y = f2bf(a2[j]) | ((unsigned int)f2bf(a3[j]) << 16);
    *(uint2*)(lds + (q * 4 + j) * 528 + kq * 8) = p;
    uint2 r;
    r.x = f2bf(b0[j]) | ((unsigned int)f2bf(b1[j]) << 16);
    r.y = f2bf(b2[j]) | ((unsigned int)f2bf(b3[j]) << 16);
    *(uint2*)(lds + (q * 4 + j) * 528 + (kq + 32) * 8) = r;
  }
  __syncthreads();
  int c = tid >> 5;                   // row 0..15 (+16i)
  int ch = tid & 31;                  // 16B chunk 0..31
#pragma unroll
  for (int i = 0; i < 4; i++) {
    int row = c + i * 16;
    uint4 val = *(const uint4*)(lds + row * 528 + ch * 16);
    *(uint4*)(dst + (size_t)(c0 + row) * DIM + r0 + ch * 8) = val;
  }
}

// ---------------- router (+ fused x->bf16 cast): fp32 logits -> softmax -> top-2 ---------------
__global__ __launch_bounds__(64) void router(const float* __restrict__ x,
                                             const float* __restrict__ gw,
                                             unsigned short* __restrict__ xbf,
                                             int* __restrict__ e0, int* __restrict__ e1,
                                             float* __restrict__ s0, float* __restrict__ s1) {
  int t = blockIdx.x;
  int lane = threadIdx.x;
  const float4* xr4 = (const float4*)(x + (size_t)t * DIM);
  float4 xv[4];
#pragma unroll
  for (int i = 0; i < 4; i++) xv[i] = xr4[i * 64 + lane];

  // fused cast: write this token's bf16 row (coalesced 512B per instr)
  ushort4* xb4 = (ushort4*)(xbf + (size_t)t * DIM);
#pragma unroll
  for (int i = 0; i < 4; i++) {
    ushort4 o;
    o.x = f2bf(xv[i].x); o.y = f2bf(xv[i].y); o.z = f2bf(xv[i].z); o.w = f2bf(xv[i].w);
    xb4[i * 64 + lane] = o;
  }
  if (t == 0) {          // zero pad row NTOK
    ushort4 zz; zz.x = zz.y = zz.z = zz.w = 0;
    ushort4* pb4 = (ushort4*)(xbf + (size_t)NTOK * DIM);
#pragma unroll
    for (int i = 0; i < 4; i++) pb4[i * 64 + lane] = zz;
  }

  float acc[NEXP];
#pragma unroll
  for (int e = 0; e < NEXP; e++) {
    const float4* g4 = (const float4*)(gw + (size_t)e * DIM);
    float a = 0.f;
#pragma unroll
    for (int i = 0; i < 4; i++) {
      float4 g = g4[i * 64 + lane];
      a += xv[i].x * g.x + xv[i].y * g.y + xv[i].z * g.z + xv[i].w * g.w;
    }
    acc[e] = a;
  }
#pragma unroll
  for (int e = 0; e < NEXP; e++) {
    float v = acc[e];
    for (int o = 32; o > 0; o >>= 1) v += __shfl_xor(v, o);
    acc[e] = v;
  }
  if (lane == 0) {
    float m = acc[0];
#pragma unroll
    for (int e = 1; e < NEXP; e++) m = fmaxf(m, acc[e]);
    float ex[NEXP]; float Z = 0.f;
#pragma unroll
    for (int e = 0; e < NEXP; e++) { ex[e] = __expf(acc[e] - m); Z += ex[e]; }
    float inv = 1.f / Z;
    float sc[NEXP];
#pragma unroll
    for (int e = 0; e < NEXP; e++) sc[e] = ex[e] * inv;
    int b0 = 0; float v0 = sc[0];
#pragma unroll
    for (int e = 1; e < NEXP; e++) if (sc[e] > v0) { v0 = sc[e]; b0 = e; }
    int b1 = -1; float v1 = -1.f;
#pragma unroll
    for (int e = 0; e < NEXP; e++) if (e != b0 && sc[e] > v1) { v1 = sc[e]; b1 = e; }
    e0[t] = b0; e1[t] = b1; s0[t] = v0; s1[t] = v1;
  }
}

// ---------------- deterministic grouped build: packed uint4 scan (128-row padding) -------------
__global__ __launch_bounds__(256) void build_groups(
    const int* __restrict__ e0, const int* __restrict__ e1,
    const float* __restrict__ s0, const float* __restrict__ s1,
    int* __restrict__ gtok, float* __restrict__ gsc, int* __restrict__ row_of,
    int* __restrict__ tile_e, int* __restrict__ tile_r0, int* __restrict__ ntiles,
    int* __restrict__ base8out) {
  __shared__ unsigned int wsum[4][4];
  __shared__ int offl[256][NEXP];
  __shared__ int lrl[256][NEXP];
  int t = threadIdx.x, lane = t & 63, wave = t >> 6;

  for (int i = t; i < ROWS_CAP; i += 256) { gtok[i] = NTOK; gsc[i] = 0.f; }  // pad -> zero row

  unsigned int pc[4] = {0, 0, 0, 0};
#pragma unroll
  for (int i = 0; i < 16; i++) {
    int ent = t * 16 + i;
    int tok = ent >> 1;
    int e = (ent & 1) ? e1[tok] : e0[tok];
    unsigned int add = 1u << ((e & 1) * 16);
    int c = e >> 1;
    if (c == 0) pc[0] += add; else if (c == 1) pc[1] += add;
    else if (c == 2) pc[2] += add; else pc[3] += add;
  }
  unsigned int incl[4] = {pc[0], pc[1], pc[2], pc[3]};
#pragma unroll
  for (int o = 1; o < 64; o <<= 1) {
    unsigned int u0 = __shfl_up(incl[0], o), u1 = __shfl_up(incl[1], o);
    unsigned int u2 = __shfl_up(incl[2], o), u3 = __shfl_up(incl[3], o);
    if (lane >= o) { incl[0] += u0; incl[1] += u1; incl[2] += u2; incl[3] += u3; }
  }
  if (lane == 63) { wsum[wave][0] = incl[0]; wsum[wave][1] = incl[1];
                    wsum[wave][2] = incl[2]; wsum[wave][3] = incl[3]; }
  __syncthreads();
  unsigned int T[4], pre[4] = {0, 0, 0, 0};
#pragma unroll
  for (int c = 0; c < 4; c++)
    T[c] = wsum[0][c] + wsum[1][c] + wsum[2][c] + wsum[3][c];
#pragma unroll
  for (int w = 0; w < 3; w++)
    if (wave > w) { pre[0] += wsum[w][0]; pre[1] += wsum[w][1];
                    pre[2] += wsum[w][2]; pre[3] += wsum[w][3]; }
  int base[NEXP + 1];
  {
    int b = 0;
#pragma unroll
    for (int e = 0; e < NEXP; e++) {
      int tot = (int)((T[e >> 1] >> ((e & 1) * 16)) & 0xFFFFu);
      base[e] = b; b += (tot + 127) & ~127;
    }
    base[NEXP] = b;
  }
#pragma unroll
  for (int e = 0; e < NEXP; e++) {
    unsigned int ex = (incl[e >> 1] + pre[e >> 1] - pc[e >> 1]);
    offl[t][e] = (int)((ex >> ((e & 1) * 16)) & 0xFFFFu);
    lrl[t][e] = 0;
  }
  if (t == 0) {
    int nt = 0;
#pragma unroll
    for (int e = 0; e < NEXP; e++) {
      int tot = (int)((T[e >> 1] >> ((e & 1) * 16)) & 0xFFFFu);
      int ntl = (tot + 127) >> 7;
      for (int i = 0; i < ntl; i++) { tile_e[nt] = e; tile_r0[nt] = base[e] + i * 128; nt++; }
    }
    for (int i = 0; i < NTOK / 128; i++) { tile_e[nt] = NEXP; tile_r0[nt] = base[NEXP] + i * 128; nt++; }
    *ntiles = nt;
    *base8out = base[NEXP];
  }
  __syncthreads();   // gtok/gsc clear complete before scatter

#pragma unroll
  for (int i = 0; i < 16; i++) {
    int ent = t * 16 + i;
    int tok = ent >> 1;
    int k = ent & 1;
    int e = k ? e1[tok] : e0[tok];
    float s = k ? s1[tok] : s0[tok];
    int pos = base[e] + offl[t][e] + lrl[t][e];
    lrl[t][e]++;
    gtok[pos] = tok; gsc[pos] = s; row_of[ent] = pos;
  }
  for (int i = t; i < NTOK; i += 256) { gtok[base[NEXP] + i] = i; gsc[base[NEXP] + i] = 1.0f; }
}

// ------- fused grouped GEMM: h = silu(s*(A*W1_e)) * (s*(A*W3_e)), A gathered from xbf ----------
// 512 threads / 8 waves on a 128x128 tile; wave-tile 32x64; 3 gloads/thread/step.
__global__ __launch_bounds__(512, 4) void gemm13(
    const unsigned short* __restrict__ xbf,
    const unsigned short* __restrict__ W1, const unsigned short* __restrict__ W1s,
    const unsigned short* __restrict__ W3, const unsigned short* __restrict__ W3s,
    unsigned short* __restrict__ H,
    const int* __restrict__ gtok, const float* __restrict__ gsc,
    const int* __restrict__ tile_e, const int* __restrict__ tile_r0,
    const int* __restrict__ ntiles) {
  if ((int)blockIdx.y >= *ntiles) return;
  int e = tile_e[blockIdx.y];
  int row0 = tile_r0[blockIdx.y];
  int col0 = blockIdx.x * 128;
  const unsigned short* B1 = (e < NEXP) ? (W1 + (size_t)e * MM) : W1s;
  const unsigned short* B3 = (e < NEXP) ? (W3 + (size_t)e * MM) : W3s;

  __shared__ __align__(16) unsigned short As[128 * 32];    // 8KB
  __shared__ __align__(16) unsigned short Bs1[128 * 32];   // 8KB
  __shared__ __align__(16) unsigned short Bs3[128 * 32];   // 8KB
  __shared__ float ss[128];

  int tid = threadIdx.x;
  int wave = tid >> 6, lane = tid & 63;
  int wrow = (wave & 3) * 32, wcol = (wave >> 2) * 64;

  if (tid < 128) ss[tid] = gsc[row0 + tid];   // synced by first K-loop barrier

  f32x4 acc1[2][4], acc3[2][4];
#pragma unroll
  for (int m = 0; m < 2; m++)
#pragma unroll
    for (int n = 0; n < 4; n++) { acc1[m][n] = f32x4{0.f,0.f,0.f,0.f}; acc3[m][n] = f32x4{0.f,0.f,0.f,0.f}; }

  // one 16B chunk per thread per buffer: chunk index = tid, row = tid>>2, k-chunk = tid&3
  int arow = tid >> 2, koff = (tid & 3) * 8;
  const unsigned short* ga  = xbf + (size_t)gtok[row0 + arow] * DIM + koff;   // per-lane gather
  const unsigned short* gb1 = B1 + (size_t)(col0 + arow) * DIM + koff;
  const unsigned short* gb3 = B3 + (size_t)(col0 + arow) * DIM + koff;
  unsigned short* lA  = As  + wave * 512;   // wave-uniform base; HW adds lane*16B
  unsigned short* lB1 = Bs1 + wave * 512;
  unsigned short* lB3 = Bs3 + wave * 512;

  int kc = lane >> 4, rl = lane & 15;

  for (int k0 = 0; k0 < DIM; k0 += 32) {
    gload_lds16(ga + k0, lA);
    gload_lds16(gb1 + k0, lB1);
    gload_lds16(gb3 + k0, lB3);
    __syncthreads();   // drains vmcnt before use

    const bf16x8* Ap  = (const bf16x8*)As;
    const bf16x8* B1p = (const bf16x8*)Bs1;
    const bf16x8* B3p = (const bf16x8*)Bs3;
    bf16x8 af[2], b1f[4], b3f[4];
#pragma unroll
    for (int m = 0; m < 2; m++) af[m] = Ap[(wrow + m * 16 + rl) * 4 + kc];
#pragma unroll
    for (int n = 0; n < 4; n++) { b1f[n] = B1p[(wcol + n * 16 + rl) * 4 + kc];
                                  b3f[n] = B3p[(wcol + n * 16 + rl) * 4 + kc]; }
#pragma unroll
    for (int m = 0; m < 2; m++)
#pragma unroll
      for (int n = 0; n < 4; n++) {
        acc1[m][n] = __builtin_amdgcn_mfma_f32_16x16x32_bf16(af[m], b1f[n], acc1[m][n], 0, 0, 0);
        acc3[m][n] = __builtin_amdgcn_mfma_f32_16x16x32_bf16(af[m], b3f[n], acc3[m][n], 0, 0, 0);
      }
    __syncthreads();   // before next stage overwrites LDS
  }

  int rj = lane >> 4, cl = lane & 15;
#pragma unroll
  for (int m = 0; m < 2; m++)
#pragma unroll
    for (int n = 0; n < 4; n++)
#pragma unroll
      for (int j = 0; j < 4; j++) {
        int lr = wrow + m * 16 + rj * 4 + j;
        float s = ss[lr];
        float a = s * acc1[m][n][j];
        float g = s * acc3[m][n][j];
        float si = a / (1.f + __expf(-a));
        H[(size_t)(row0 + lr) * DIM + (col0 + wcol + n * 16 + cl)] = f2bf(si * g);
      }
}

// ---------------- grouped GEMM: rout = H * W2_e (fp32 out); 512 threads ------------------------
__global__ __launch_bounds__(512, 4) void gemm2(
    const unsigned short* __restrict__ A, const unsigned short* __restrict__ W,
    const unsigned short* __restrict__ Wsh, float* __restrict__ C,
    const int* __restrict__ tile_e, const int* __restrict__ tile_r0,
    const int* __restrict__ ntiles) {
  if ((int)blockIdx.y >= *ntiles) return;
  int e = tile_e[blockIdx.y];
  int row0 = tile_r0[blockIdx.y];
  int col0 = blockIdx.x * 128;
  const unsigned short* B = (e < NEXP) ? (W + (size_t)e * MM) : Wsh;

  __shared__ __align__(16) unsigned short As[128 * 32];
  __shared__ __align__(16) unsigned short Bs[128 * 32];

  int tid = threadIdx.x;
  int wave = tid >> 6, lane = tid & 63;
  int wrow = (wave & 3) * 32, wcol = (wave >> 2) * 64;

  f32x4 acc[2][4];
#pragma unroll
  for (int m = 0; m < 2; m++)
#pragma unroll
    for (int n = 0; n < 4; n++) acc[m][n] = f32x4{0.f, 0.f, 0.f, 0.f};

  int arow = tid >> 2, koff = (tid & 3) * 8;
  const unsigned short* ga = A + (size_t)(row0 + arow) * DIM + koff;
  const unsigned short* gb = B + (size_t)(col0 + arow) * DIM + koff;
  unsigned short* lA = As + wave * 512;
  unsigned short* lB = Bs + wave * 512;

  int kc = lane >> 4, rl = lane & 15;

  for (int k0 = 0; k0 < DIM; k0 += 32) {
    gload_lds16(ga + k0, lA);
    gload_lds16(gb + k0, lB);
    __syncthreads();

    const bf16x8* Ap = (const bf16x8*)As;
    const bf16x8* Bp = (const bf16x8*)Bs;
    bf16x8 af[2], bfr[4];
#pragma unroll
    for (int m = 0; m < 2; m++) af[m] = Ap[(wrow + m * 16 + rl) * 4 + kc];
#pragma unroll
    for (int n = 0; n < 4; n++) bfr[n] = Bp[(wcol + n * 16 + rl) * 4 + kc];
#pragma unroll
    for (int m = 0; m < 2; m++)
#pragma unroll
      for (int n = 0; n < 4; n++)
        acc[m][n] = __builtin_amdgcn_mfma_f32_16x16x32_bf16(af[m], bfr[n], acc[m][n], 0, 0, 0);
    __syncthreads();
  }

  int rj = lane >> 4, cl = lane & 15;
#pragma unroll
  for (int m = 0; m < 2; m++)
#pragma unroll
    for (int n = 0; n < 4; n++)
#pragma unroll
      for (int j = 0; j < 4; j++) {
        int r = row0 + wrow + m * 16 + rj * 4 + j;
        int c = col0 + wcol + n * 16 + cl;
        C[(size_t)r * DIM + c] = acc[m][n][j];
      }
}

// ---------------- combine: out[t] = rout[r0] + rout[r1] + rout[shared] -------------------------
__global__ __launch_bounds__(256) void combine(const float* __restrict__ rout,
                                               const int* __restrict__ row_of,
                                               const int* __restrict__ base8,
                                               float* __restrict__ out) {
  int t = blockIdx.x;
  int c = threadIdx.x * 4;
  int r0 = row_of[2 * t], r1 = row_of[2 * t + 1];
  int rs = *base8 + t;
  float4 v0 = *(const float4*)(rout + (size_t)r0 * DIM + c);
  float4 v1 = *(const float4*)(rout + (size_t)r1 * DIM + c);
  float4 v2 = *(const float4*)(rout + (size_t)rs * DIM + c);
  float4 o;
  o.x = v0.x + v1.x + v2.x;
  o.y = v0.y + v1.y + v2.y;
  o.z = v0.z + v1.z + v2.z;
  o.w = v0.w + v1.w + v2.w;
  *(float4*)(out + (size_t)t * DIM + c) = o;
}

extern "C" void kernel_launch(void* const* d_in, const int* in_sizes, int n_in,
                              void* d_out, int out_size, void* d_ws, size_t ws_size,
                              hipStream_t stream) {
  const float* x   = (const float*)d_in[0];
  const float* gw  = (const float*)d_in[1];
  const float* w1  = (const float*)d_in[2];
  const float* w2  = (const float*)d_in[3];
  const float* w3  = (const float*)d_in[4];
  const float* w1s = (const float*)d_in[5];
  const float* w2s = (const float*)d_in[6];
  const float* w3s = (const float*)d_in[7];
  float* out = (float*)d_out;
  char* ws = (char*)d_ws;

  const size_t MB = 1ull << 20;
  unsigned short* w1t  = (unsigned short*)(ws + 0 * MB);    // 16MB [8][1024][1024] B^T bf16
  unsigned short* w3t  = (unsigned short*)(ws + 16 * MB);   // 16MB
  unsigned short* w2t  = (unsigned short*)(ws + 32 * MB);   // 16MB
  unsigned short* w1st = (unsigned short*)(ws + 48 * MB);   // 2MB
  unsigned short* w3st = (unsigned short*)(ws + 50 * MB);   // 2MB
  unsigned short* w2st = (unsigned short*)(ws + 52 * MB);   // 2MB
  unsigned short* xbf  = (unsigned short*)(ws + 54 * MB);   // 4MB+  [NTOK+1][1024] bf16
  unsigned short* hbuf = (unsigned short*)(ws + 60 * MB);   // 16MB [8192][1024] bf16
  float* rout = (float*)(ws + 76 * MB);                     // 32MB [8192][1024] fp32
  char* meta = ws + 108 * MB;
  int*   e0p    = (int*)meta;
  int*   e1p    = e0p + NTOK;
  float* s0p    = (float*)(e1p + NTOK);
  float* s1p    = s0p + NTOK;
  int*   gtok   = (int*)(s1p + NTOK);
  float* gsc    = (float*)(gtok + ROWS_CAP);
  int*   row_of = (int*)(gsc + ROWS_CAP);
  int*   tile_e = row_of + NENT;
  int*   tile_r0= tile_e + MAX_TILES;
  int*   ntiles = tile_r0 + MAX_TILES;
  int*   base8  = ntiles + 1;

  router<<<NTOK, 64, 0, stream>>>(x, gw, xbf, e0p, e1p, s0p, s1p);
  build_groups<<<1, 256, 0, stream>>>(e0p, e1p, s0p, s1p, gtok, gsc, row_of,
                                      tile_e, tile_r0, ntiles, base8);
  transpose_all<<<dim3(16, 4, 27), 512, 0, stream>>>(
      w1, w3, w2, w1s, w3s, w2s, w1t, w3t, w2t, w1st, w3st, w2st);

  dim3 gg(8, MAX_TILES);
  gemm13<<<gg, 512, 0, stream>>>(xbf, w1t, w1st, w3t, w3st, hbuf,
                                 gtok, gsc, tile_e, tile_r0, ntiles);
  gemm2<<<gg, 512, 0, stream>>>(hbuf, w2t, w2st, rout, tile_e, tile_r0, ntiles);

  combine<<<NTOK, 256, 0, stream>>>(rout, row_of, base8, out);
}

// Round 12
// 120.137 us; speedup vs baseline: 1.2071x; 1.0165x over previous
//
#include <hip/hip_runtime.h>
#include <hip/hip_bf16.h>

// MoE top-2 + shared expert, bf16 MFMA path. Round 12.
// vs R10 (122.1us best): W^T is stored in BRICK layout — 8KB bricks of
// [128n][32k] in GEMM-stage chunk order (chunk tid -> row=tid>>2, koff=tid&3).
// Transpose writes 32KB fully-contiguous per block (single writer, 1KB/wave
// stores); GEMM B-staging reads become pure linear (brick + tid*16B).
// R11's tr-read path (failed correctness) fully reverted. Router+cast fused,
// build/combine/GEMM structure = R10 winning forms. No atomics.

#define DIM 1024
#define NTOK 2048
#define NEXP 8
#define NENT 4096          // NTOK * 2
#define ROWS_CAP 8192      // padded grouped rows upper bound
#define MAX_TILES 64
#define MM (DIM * DIM)

typedef float f32x4 __attribute__((ext_vector_type(4)));
typedef __bf16 bf16x8 __attribute__((ext_vector_type(8)));

__device__ __forceinline__ unsigned short f2bf(float f) {
  unsigned int u = __builtin_bit_cast(unsigned int, f);
  unsigned int r = u + 0x7FFFu + ((u >> 16) & 1u);   // RNE
  return (unsigned short)(r >> 16);
}
__device__ __forceinline__ void gload_lds16(const unsigned short* g, unsigned short* l) {
  __builtin_amdgcn_global_load_lds((__attribute__((address_space(1))) const void*)g,
                                   (__attribute__((address_space(3))) void*)l, 16, 0, 0);
}

// ---------------- weight transpose+cast v4 (BRICK output), 27 z-slices -------------------------
// Block = 128n x 128k tile -> 4 consecutive bricks (32KB contiguous).
// Brick (n_blk, kc): 512 chunks of 16B; chunk c -> (row=c>>2, koff=c&3),
// element j: W^T[n_blk*128+row][kc*32+koff*8+j].
// LDS: [128 rows][16 ch x 16B], chunk position swizzled ch^=(row&15).
__global__ __launch_bounds__(512) void transpose_all(
    const float* __restrict__ w1, const float* __restrict__ w3, const float* __restrict__ w2,
    const float* __restrict__ w1s, const float* __restrict__ w3s, const float* __restrict__ w2s,
    unsigned short* __restrict__ w1t, unsigned short* __restrict__ w3t,
    unsigned short* __restrict__ w2t, unsigned short* __restrict__ w1st,
    unsigned short* __restrict__ w3st, unsigned short* __restrict__ w2st) {
  __shared__ __align__(16) unsigned short lds[128 * 128];   // 32KB
  int z = blockIdx.z;
  const float* src; unsigned short* dst;
  if (z < 8)       { src = w1 + (size_t)z * MM;        dst = w1t + (size_t)z * MM; }
  else if (z < 16) { src = w3 + (size_t)(z - 8) * MM;  dst = w3t + (size_t)(z - 8) * MM; }
  else if (z < 24) { src = w2 + (size_t)(z - 16) * MM; dst = w2t + (size_t)(z - 16) * MM; }
  else if (z == 24){ src = w1s; dst = w1st; }
  else if (z == 25){ src = w3s; dst = w3st; }
  else             { src = w2s; dst = w2st; }
  int n_blk = blockIdx.x;             // 0..7
  int k_blk = blockIdx.y;             // 0..7
  int c0 = n_blk * 128, r0 = k_blk * 128;
  int tid = threadIdx.x;
  int q = tid & 31;                   // n-quad (n = 4q..4q+3)
  int kq0 = tid >> 5;                 // k-quad 0..15; second pass at +16

  // phase 1: 8 float4 loads (all issued up front), 2x 4x4 micro-transpose,
  // 8x ds_write_b64 into swizzled chunk positions
  const float* sp0 = src + (size_t)(r0 + kq0 * 4) * DIM + c0 + q * 4;
  const float* sp1 = sp0 + (size_t)64 * DIM;     // kq0+16
  float4 v0 = *(const float4*)(sp0 + 0 * DIM);
  float4 v1 = *(const float4*)(sp0 + 1 * DIM);
  float4 v2 = *(const float4*)(sp0 + 2 * DIM);
  float4 v3 = *(const float4*)(sp0 + 3 * DIM);
  float4 v4 = *(const float4*)(sp1 + 0 * DIM);
  float4 v5 = *(const float4*)(sp1 + 1 * DIM);
  float4 v6 = *(const float4*)(sp1 + 2 * DIM);
  float4 v7 = *(const float4*)(sp1 + 3 * DIM);
  {
    float a0[4] = {v0.x, v0.y, v0.z, v0.w};
    float a1[4] = {v1.x, v1.y, v1.z, v1.w};
    float a2[4] = {v2.x, v2.y, v2.z, v2.w};
    float a3[4] = {v3.x, v3.y, v3.z, v3.w};
    float b0[4] = {v4.x, v4.y, v4.z, v4.w};
    float b1[4] = {v5.x, v5.y, v5.z, v5.w};
    float b2[4] = {v6.x, v6.y, v6.z, v6.w};
    float b3[4] = {v7.x, v7.y, v7.z, v7.w};
#pragma unroll
    for (int j = 0; j < 4; j++) {
      int row = q * 4 + j;
      {
        int kq = kq0;
        int ch = kq >> 1, half = kq & 1;
        unsigned int off = (unsigned int)row * 128 + ((ch ^ (row & 15)) * 8 + half * 4);
        uint2 p;
        p.x = f2bf(a0[j]) | ((unsigned int)f2bf(a1[j]) << 16);
        p.y = f2bf(a2[j]) | ((unsigned int)f2bf(a3[j]) << 16);
        *(uint2*)(lds + off) = p;
      }
      {
        int kq = kq0 + 16;
        int ch = kq >> 1, half = kq & 1;
        unsigned int off = (unsigned int)row * 128 + ((ch ^ (row & 15)) * 8 + half * 4);
        uint2 p;
        p.x = f2bf(b0[j]) | ((unsigned int)f2bf(b1[j]) << 16);
        p.y = f2bf(b2[j]) | ((unsigned int)f2bf(b3[j]) << 16);
        *(uint2*)(lds + off) = p;
      }
    }
  }
  __syncthreads();

  // phase 2: 4 uint4 reads (swizzled), 4 contiguous uint4 stores into bricks
  size_t bbase = ((size_t)n_blk * 32 + (size_t)k_blk * 4) * 4096;
#pragma unroll
  for (int i = 0; i < 4; i++) {
    int g = tid + i * 512;            // output chunk 0..2047
    int kcr = g >> 9;                 // brick 0..3 (relative kc)
    int c = g & 511;
    int row = c >> 2, koff = c & 3;
    int ch = kcr * 4 + koff;          // k-chunk 0..15
    uint4 val = *(const uint4*)(lds + (unsigned int)row * 128 + (ch ^ (row & 15)) * 8);
    *(uint4*)(dst + bbase + (size_t)g * 8) = val;
  }
}

// ---------------- router (+ fused x->bf16 cast): fp32 logits -> softmax -> top-2 ---------------
__global__ __launch_bounds__(64) void router(const float* __restrict__ x,
                                             const float* __restrict__ gw,
                                             unsigned short* __restrict__ xbf,
                                             int* __restrict__ e0, int* __restrict__ e1,
                                             float* __restrict__ s0, float* __restrict__ s1) {
  int t = blockIdx.x;
  int lane = threadIdx.x;
  const float4* xr4 = (const float4*)(x + (size_t)t * DIM);
  float4 xv[4];
#pragma unroll
  for (int i = 0; i < 4; i++) xv[i] = xr4[i * 64 + lane];

  ushort4* xb4 = (ushort4*)(xbf + (size_t)t * DIM);
#pragma unroll
  for (int i = 0; i < 4; i++) {
    ushort4 o;
    o.x = f2bf(xv[i].x); o.y = f2bf(xv[i].y); o.z = f2bf(xv[i].z); o.w = f2bf(xv[i].w);
    xb4[i * 64 + lane] = o;
  }
  if (t == 0) {          // zero pad row NTOK
    ushort4 zz; zz.x = zz.y = zz.z = zz.w = 0;
    ushort4* pb4 = (ushort4*)(xbf + (size_t)NTOK * DIM);
#pragma unroll
    for (int i = 0; i < 4; i++) pb4[i * 64 + lane] = zz;
  }

  float acc[NEXP];
#pragma unroll
  for (int e = 0; e < NEXP; e++) {
    const float4* g4 = (const float4*)(gw + (size_t)e * DIM);
    float a = 0.f;
#pragma unroll
    for (int i = 0; i < 4; i++) {
      float4 g = g4[i * 64 + lane];
      a += xv[i].x * g.x + xv[i].y * g.y + xv[i].z * g.z + xv[i].w * g.w;
    }
    acc[e] = a;
  }
#pragma unroll
  for (int e = 0; e < NEXP; e++) {
    float v = acc[e];
    for (int o = 32; o > 0; o >>= 1) v += __shfl_xor(v, o);
    acc[e] = v;
  }
  if (lane == 0) {
    float m = acc[0];
#pragma unroll
    for (int e = 1; e < NEXP; e++) m = fmaxf(m, acc[e]);
    float ex[NEXP]; float Z = 0.f;
#pragma unroll
    for (int e = 0; e < NEXP; e++) { ex[e] = __expf(acc[e] - m); Z += ex[e]; }
    float inv = 1.f / Z;
    float sc[NEXP];
#pragma unroll
    for (int e = 0; e < NEXP; e++) sc[e] = ex[e] * inv;
    int b0 = 0; float v0 = sc[0];
#pragma unroll
    for (int e = 1; e < NEXP; e++) if (sc[e] > v0) { v0 = sc[e]; b0 = e; }
    int b1 = -1; float v1 = -1.f;
#pragma unroll
    for (int e = 0; e < NEXP; e++) if (e != b0 && sc[e] > v1) { v1 = sc[e]; b1 = e; }
    e0[t] = b0; e1[t] = b1; s0[t] = v0; s1[t] = v1;
  }
}

// ---------------- deterministic grouped build: packed uint4 scan (128-row padding) -------------
__global__ __launch_bounds__(256) void build_groups(
    const int* __restrict__ e0, const int* __restrict__ e1,
    const float* __restrict__ s0, const float* __restrict__ s1,
    int* __restrict__ gtok, float* __restrict__ gsc, int* __restrict__ row_of,
    int* __restrict__ tile_e, int* __restrict__ tile_r0, int* __restrict__ ntiles,
    int* __restrict__ base8out) {
  __shared__ unsigned int wsum[4][4];
  __shared__ int offl[256][NEXP];
  __shared__ int lrl[256][NEXP];
  int t = threadIdx.x, lane = t & 63, wave = t >> 6;

  for (int i = t; i < ROWS_CAP; i += 256) { gtok[i] = NTOK; gsc[i] = 0.f; }  // pad -> zero row

  unsigned int pc[4] = {0, 0, 0, 0};
#pragma unroll
  for (int i = 0; i < 16; i++) {
    int ent = t * 16 + i;
    int tok = ent >> 1;
    int e = (ent & 1) ? e1[tok] : e0[tok];
    unsigned int add = 1u << ((e & 1) * 16);
    int c = e >> 1;
    if (c == 0) pc[0] += add; else if (c == 1) pc[1] += add;
    else if (c == 2) pc[2] += add; else pc[3] += add;
  }
  unsigned int incl[4] = {pc[0], pc[1], pc[2], pc[3]};
#pragma unroll
  for (int o = 1; o < 64; o <<= 1) {
    unsigned int u0 = __shfl_up(incl[0], o), u1 = __shfl_up(incl[1], o);
    unsigned int u2 = __shfl_up(incl[2], o), u3 = __shfl_up(incl[3], o);
    if (lane >= o) { incl[0] += u0; incl[1] += u1; incl[2] += u2; incl[3] += u3; }
  }
  if (lane == 63) { wsum[wave][0] = incl[0]; wsum[wave][1] = incl[1];
                    wsum[wave][2] = incl[2]; wsum[wave][3] = incl[3]; }
  __syncthreads();
  unsigned int T[4], pre[4] = {0, 0, 0, 0};
#pragma unroll
  for (int c = 0; c < 4; c++)
    T[c] = wsum[0][c] + wsum[1][c] + wsum[2][c] + wsum[3][c];
#pragma unroll
  for (int w = 0; w < 3; w++)
    if (wave > w) { pre[0] += wsum[w][0]; pre[1] += wsum[w][1];
                    pre[2] += wsum[w][2]; pre[3] += wsum[w][3]; }
  int base[NEXP + 1];
  {
    int b = 0;
#pragma unroll
    for (int e = 0; e < NEXP; e++) {
      int tot = (int)((T[e >> 1] >> ((e & 1) * 16)) & 0xFFFFu);
      base[e] = b; b += (tot + 127) & ~127;
    }
    base[NEXP] = b;
  }
#pragma unroll
  for (int e = 0; e < NEXP; e++) {
    unsigned int ex = (incl[e >> 1] + pre[e >> 1] - pc[e >> 1]);
    offl[t][e] = (int)((ex >> ((e & 1) * 16)) & 0xFFFFu);
    lrl[t][e] = 0;
  }
  if (t == 0) {
    int nt = 0;
#pragma unroll
    for (int e = 0; e < NEXP; e++) {
      int tot = (int)((T[e >> 1] >> ((e & 1) * 16)) & 0xFFFFu);
      int ntl = (tot + 127) >> 7;
      for (int i = 0; i < ntl; i++) { tile_e[nt] = e; tile_r0[nt] = base[e] + i * 128; nt++; }
    }
    for (int i = 0; i < NTOK / 128; i++) { tile_e[nt] = NEXP; tile_r0[nt] = base[NEXP] + i * 128; nt++; }
    *ntiles = nt;
    *base8out = base[NEXP];
  }
  __syncthreads();   // gtok/gsc clear complete before scatter

#pragma unroll
  for (int i = 0; i < 16; i++) {
    int ent = t * 16 + i;
    int tok = ent >> 1;
    int k = ent & 1;
    int e = k ? e1[tok] : e0[tok];
    float s = k ? s1[tok] : s0[tok];
    int pos = base[e] + offl[t][e] + lrl[t][e];
    lrl[t][e]++;
    gtok[pos] = tok; gsc[pos] = s; row_of[ent] = pos;
  }
  for (int i = t; i < NTOK; i += 256) { gtok[base[NEXP] + i] = i; gsc[base[NEXP] + i] = 1.0f; }
}

// ------- fused grouped GEMM: h = silu(s*(A*W1_e)) * (s*(A*W3_e)), W^T in brick layout ----------
// 512 thr / 8 waves, 128x128 tile, wave-tile 32x64. B-staging = linear brick read.
__global__ __launch_bounds__(512, 4) void gemm13(
    const unsigned short* __restrict__ xbf,
    const unsigned short* __restrict__ W1, const unsigned short* __restrict__ W1s,
    const unsigned short* __restrict__ W3, const unsigned short* __restrict__ W3s,
    unsigned short* __restrict__ H,
    const int* __restrict__ gtok, const float* __restrict__ gsc,
    const int* __restrict__ tile_e, const int* __restrict__ tile_r0,
    const int* __restrict__ ntiles) {
  if ((int)blockIdx.y >= *ntiles) return;
  int e = tile_e[blockIdx.y];
  int row0 = tile_r0[blockIdx.y];
  int col0 = blockIdx.x * 128;
  const unsigned short* B1 = (e < NEXP) ? (W1 + (size_t)e * MM) : W1s;
  const unsigned short* B3 = (e < NEXP) ? (W3 + (size_t)e * MM) : W3s;

  __shared__ __align__(16) unsigned short As[128 * 32];    // 8KB
  __shared__ __align__(16) unsigned short Bs1[128 * 32];   // 8KB (brick image)
  __shared__ __align__(16) unsigned short Bs3[128 * 32];
  __shared__ float ss[128];

  int tid = threadIdx.x;
  int wave = tid >> 6, lane = tid & 63;
  int wrow = (wave & 3) * 32, wcol = (wave >> 2) * 64;

  if (tid < 128) ss[tid] = gsc[row0 + tid];   // synced by first K-loop barrier

  f32x4 acc1[2][4], acc3[2][4];
#pragma unroll
  for (int m = 0; m < 2; m++)
#pragma unroll
    for (int n = 0; n < 4; n++) { acc1[m][n] = f32x4{0.f,0.f,0.f,0.f}; acc3[m][n] = f32x4{0.f,0.f,0.f,0.f}; }

  // A: per-lane gather (row tid>>2 of grouped tile, k-chunk tid&3)
  int arow = tid >> 2, koff = (tid & 3) * 8;
  const unsigned short* ga  = xbf + (size_t)gtok[row0 + arow] * DIM + koff;
  // B: linear brick read — brick (col0>>7, k0>>5), chunk tid
  const unsigned short* gb1 = B1 + ((size_t)(col0 >> 7) * 32) * 4096 + (size_t)tid * 8;
  const unsigned short* gb3 = B3 + ((size_t)(col0 >> 7) * 32) * 4096 + (size_t)tid * 8;
  unsigned short* lA  = As  + wave * 512;   // wave-uniform base; HW adds lane*16B
  unsigned short* lB1 = Bs1 + wave * 512;
  unsigned short* lB3 = Bs3 + wave * 512;

  int kc = lane >> 4, rl = lane & 15;

  for (int k0 = 0; k0 < DIM; k0 += 32) {
    size_t boff = (size_t)(k0 >> 5) * 4096;
    gload_lds16(ga + k0, lA);
    gload_lds16(gb1 + boff, lB1);
    gload_lds16(gb3 + boff, lB3);
    __syncthreads();   // drains vmcnt before use

    const bf16x8* Ap  = (const bf16x8*)As;
    const bf16x8* B1p = (const bf16x8*)Bs1;
    const bf16x8* B3p = (const bf16x8*)Bs3;
    bf16x8 af[2], b1f[4], b3f[4];
#pragma unroll
    for (int m = 0; m < 2; m++) af[m] = Ap[(wrow + m * 16 + rl) * 4 + kc];
#pragma unroll
    for (int n = 0; n < 4; n++) { b1f[n] = B1p[(wcol + n * 16 + rl) * 4 + kc];
                                  b3f[n] = B3p[(wcol + n * 16 + rl) * 4 + kc]; }
#pragma unroll
    for (int m = 0; m < 2; m++)
#pragma unroll
      for (int n = 0; n < 4; n++) {
        acc1[m][n] = __builtin_amdgcn_mfma_f32_16x16x32_bf16(af[m], b1f[n], acc1[m][n], 0, 0, 0);
        acc3[m][n] = __builtin_amdgcn_mfma_f32_16x16x32_bf16(af[m], b3f[n], acc3[m][n], 0, 0, 0);
      }
    __syncthreads();   // before next stage overwrites LDS
  }

  int rj = lane >> 4, cl = lane & 15;
#pragma unroll
  for (int m = 0; m < 2; m++)
#pragma unroll
    for (int n = 0; n < 4; n++)
#pragma unroll
      for (int j = 0; j < 4; j++) {
        int lr = wrow + m * 16 + rj * 4 + j;
        float s = ss[lr];
        float a = s * acc1[m][n][j];
        float g = s * acc3[m][n][j];
        float si = a / (1.f + __expf(-a));
        H[(size_t)(row0 + lr) * DIM + (col0 + wcol + n * 16 + cl)] = f2bf(si * g);
      }
}

// ---------------- grouped GEMM: rout = H * W2_e (fp32 out); W2^T bricks ------------------------
__global__ __launch_bounds__(512, 4) void gemm2(
    const unsigned short* __restrict__ A, const unsigned short* __restrict__ W,
    const unsigned short* __restrict__ Wsh, float* __restrict__ C,
    const int* __restrict__ tile_e, const int* __restrict__ tile_r0,
    const int* __restrict__ ntiles) {
  if ((int)blockIdx.y >= *ntiles) return;
  int e = tile_e[blockIdx.y];
  int row0 = tile_r0[blockIdx.y];
  int col0 = blockIdx.x * 128;
  const unsigned short* B = (e < NEXP) ? (W + (size_t)e * MM) : Wsh;

  __shared__ __align__(16) unsigned short As[128 * 32];
  __shared__ __align__(16) unsigned short Bs[128 * 32];

  int tid = threadIdx.x;
  int wave = tid >> 6, lane = tid & 63;
  int wrow = (wave & 3) * 32, wcol = (wave >> 2) * 64;

  f32x4 acc[2][4];
#pragma unroll
  for (int m = 0; m < 2; m++)
#pragma unroll
    for (int n = 0; n < 4; n++) acc[m][n] = f32x4{0.f, 0.f, 0.f, 0.f};

  int arow = tid >> 2, koff = (tid & 3) * 8;
  const unsigned short* ga = A + (size_t)(row0 + arow) * DIM + koff;
  const unsigned short* gb = B + ((size_t)(col0 >> 7) * 32) * 4096 + (size_t)tid * 8;
  unsigned short* lA = As + wave * 512;
  unsigned short* lB = Bs + wave * 512;

  int kc = lane >> 4, rl = lane & 15;

  for (int k0 = 0; k0 < DIM; k0 += 32) {
    size_t boff = (size_t)(k0 >> 5) * 4096;
    gload_lds16(ga + k0, lA);
    gload_lds16(gb + boff, lB);
    __syncthreads();

    const bf16x8* Ap = (const bf16x8*)As;
    const bf16x8* Bp = (const bf16x8*)Bs;
    bf16x8 af[2], bfr[4];
#pragma unroll
    for (int m = 0; m < 2; m++) af[m] = Ap[(wrow + m * 16 + rl) * 4 + kc];
#pragma unroll
    for (int n = 0; n < 4; n++) bfr[n] = Bp[(wcol + n * 16 + rl) * 4 + kc];
#pragma unroll
    for (int m = 0; m < 2; m++)
#pragma unroll
      for (int n = 0; n < 4; n++)
        acc[m][n] = __builtin_amdgcn_mfma_f32_16x16x32_bf16(af[m], bfr[n], acc[m][n], 0, 0, 0);
    __syncthreads();
  }

  int rj = lane >> 4, cl = lane & 15;
#pragma unroll
  for (int m = 0; m < 2; m++)
#pragma unroll
    for (int n = 0; n < 4; n++)
#pragma unroll
      for (int j = 0; j < 4; j++) {
        int r = row0 + wrow + m * 16 + rj * 4 + j;
        int c = col0 + wcol + n * 16 + cl;
        C[(size_t)r * DIM + c] = acc[m][n][j];
      }
}

// ---------------- combine: out[t] = rout[r0] + rout[r1] + rout[shared] -------------------------
__global__ __launch_bounds__(256) void combine(const float* __restrict__ rout,
                                               const int* __restrict__ row_of,
                                               const int* __restrict__ base8,
                                               float* __restrict__ out) {
  int t = blockIdx.x;
  int c = threadIdx.x * 4;
  int r0 = row_of[2 * t], r1 = row_of[2 * t + 1];
  int rs = *base8 + t;
  float4 v0 = *(const float4*)(rout + (size_t)r0 * DIM + c);
  float4 v1 = *(const float4*)(rout + (size_t)r1 * DIM + c);
  float4 v2 = *(const float4*)(rout + (size_t)rs * DIM + c);
  float4 o;
  o.x = v0.x + v1.x + v2.x;
  o.y = v0.y + v1.y + v2.y;
  o.z = v0.z + v1.z + v2.z;
  o.w = v0.w + v1.w + v2.w;
  *(float4*)(out + (size_t)t * DIM + c) = o;
}

extern "C" void kernel_launch(void* const* d_in, const int* in_sizes, int n_in,
                              void* d_out, int out_size, void* d_ws, size_t ws_size,
                              hipStream_t stream) {
  const float* x   = (const float*)d_in[0];
  const float* gw  = (const float*)d_in[1];
  const float* w1  = (const float*)d_in[2];
  const float* w2  = (const float*)d_in[3];
  const float* w3  = (const float*)d_in[4];
  const float* w1s = (const float*)d_in[5];
  const float* w2s = (const float*)d_in[6];
  const float* w3s = (const float*)d_in[7];
  float* out = (float*)d_out;
  char* ws = (char*)d_ws;

  const size_t MB = 1ull << 20;
  unsigned short* w1t  = (unsigned short*)(ws + 0 * MB);    // 16MB [8] brick-layout W1^T
  unsigned short* w3t  = (unsigned short*)(ws + 16 * MB);   // 16MB
  unsigned short* w2t  = (unsigned short*)(ws + 32 * MB);   // 16MB
  unsigned short* w1st = (unsigned short*)(ws + 48 * MB);   // 2MB
  unsigned short* w3st = (unsigned short*)(ws + 50 * MB);   // 2MB
  unsigned short* w2st = (unsigned short*)(ws + 52 * MB);   // 2MB
  unsigned short* xbf  = (unsigned short*)(ws + 54 * MB);   // 4MB+  [NTOK+1][1024] bf16
  unsigned short* hbuf = (unsigned short*)(ws + 60 * MB);   // 16MB [8192][1024] bf16
  float* rout = (float*)(ws + 76 * MB);                     // 32MB [8192][1024] fp32
  char* meta = ws + 108 * MB;
  int*   e0p    = (int*)meta;
  int*   e1p    = e0p + NTOK;
  float* s0p    = (float*)(e1p + NTOK);
  float* s1p    = s0p + NTOK;
  int*   gtok   = (int*)(s1p + NTOK);
  float* gsc    = (float*)(gtok + ROWS_CAP);
  int*   row_of = (int*)(gsc + ROWS_CAP);
  int*   tile_e = row_of + NENT;
  int*   tile_r0= tile_e + MAX_TILES;
  int*   ntiles = tile_r0 + MAX_TILES;
  int*   base8  = ntiles + 1;

  router<<<NTOK, 64, 0, stream>>>(x, gw, xbf, e0p, e1p, s0p, s1p);
  build_groups<<<1, 256, 0, stream>>>(e0p, e1p, s0p, s1p, gtok, gsc, row_of,
                                      tile_e, tile_r0, ntiles, base8);
  transpose_all<<<dim3(8, 8, 27), 512, 0, stream>>>(
      w1, w3, w2, w1s, w3s, w2s, w1t, w3t, w2t, w1st, w3st, w2st);

  dim3 gg(8, MAX_TILES);
  gemm13<<<gg, 512, 0, stream>>>(xbf, w1t, w1st, w3t, w3st, hbuf,
                                 gtok, gsc, tile_e, tile_r0, ntiles);
  gemm2<<<gg, 512, 0, stream>>>(hbuf, w2t, w2st, rout, tile_e, tile_r0, ntiles);

  combine<<<NTOK, 256, 0, stream>>>(rout, row_of, base8, out);
}

// Round 13
// 110.787 us; speedup vs baseline: 1.3089x; 1.0844x over previous
//
#include <hip/hip_runtime.h>
#include <hip/hip_bf16.h>

// MoE top-2 + shared expert, bf16 MFMA path. Round 13.
// vs R12 (120.1us): transpose is co-scheduled, not faster — 6 variants all hit
// ~48us (latency-floor, all pipes idle). K1 = router ∪ transpose(w1,w3);
// K3 = gemm13 ∪ transpose(w2). Grid-role partitioning inside one kernel;
// dependencies respected by stream order (router⊥t13, gemm13⊥t2).
// GEMM/build/combine bodies = R12 verbatim (brick W^T layout). No atomics.

#define DIM 1024
#define NTOK 2048
#define NEXP 8
#define NENT 4096          // NTOK * 2
#define ROWS_CAP 8192      // padded grouped rows upper bound
#define MAX_TILES 64
#define MM (DIM * DIM)

typedef float f32x4 __attribute__((ext_vector_type(4)));
typedef __bf16 bf16x8 __attribute__((ext_vector_type(8)));

__device__ __forceinline__ unsigned short f2bf(float f) {
  unsigned int u = __builtin_bit_cast(unsigned int, f);
  unsigned int r = u + 0x7FFFu + ((u >> 16) & 1u);   // RNE
  return (unsigned short)(r >> 16);
}
__device__ __forceinline__ void gload_lds16(const unsigned short* g, unsigned short* l) {
  __builtin_amdgcn_global_load_lds((__attribute__((address_space(1))) const void*)g,
                                   (__attribute__((address_space(3))) void*)l, 16, 0, 0);
}

// ---------------- brick transpose device fn (R12-verified): 128n x 128k tile -> 4 bricks -------
// Brick (n_blk, kc): 512 x 16B chunks; chunk c -> (row=c>>2, koff=c&3);
// LDS [128][128 bf16] with chunk swizzle ch^=(row&15). Requires 512 threads.
__device__ __forceinline__ void brick_transpose(const float* __restrict__ src,
                                                unsigned short* __restrict__ dst,
                                                int n_blk, int k_blk,
                                                unsigned short* lds) {
  int c0 = n_blk * 128, r0 = k_blk * 128;
  int tid = threadIdx.x;
  int q = tid & 31;                   // n-quad (n = 4q..4q+3)
  int kq0 = tid >> 5;                 // k-quad 0..15; second pass at +16

  const float* sp0 = src + (size_t)(r0 + kq0 * 4) * DIM + c0 + q * 4;
  const float* sp1 = sp0 + (size_t)64 * DIM;     // kq0+16
  float4 v0 = *(const float4*)(sp0 + 0 * DIM);
  float4 v1 = *(const float4*)(sp0 + 1 * DIM);
  float4 v2 = *(const float4*)(sp0 + 2 * DIM);
  float4 v3 = *(const float4*)(sp0 + 3 * DIM);
  float4 v4 = *(const float4*)(sp1 + 0 * DIM);
  float4 v5 = *(const float4*)(sp1 + 1 * DIM);
  float4 v6 = *(const float4*)(sp1 + 2 * DIM);
  float4 v7 = *(const float4*)(sp1 + 3 * DIM);
  {
    float a0[4] = {v0.x, v0.y, v0.z, v0.w};
    float a1[4] = {v1.x, v1.y, v1.z, v1.w};
    float a2[4] = {v2.x, v2.y, v2.z, v2.w};
    float a3[4] = {v3.x, v3.y, v3.z, v3.w};
    float b0[4] = {v4.x, v4.y, v4.z, v4.w};
    float b1[4] = {v5.x, v5.y, v5.z, v5.w};
    float b2[4] = {v6.x, v6.y, v6.z, v6.w};
    float b3[4] = {v7.x, v7.y, v7.z, v7.w};
#pragma unroll
    for (int j = 0; j < 4; j++) {
      int row = q * 4 + j;
      {
        int kq = kq0;
        int ch = kq >> 1, half = kq & 1;
        unsigned int off = (unsigned int)row * 128 + ((ch ^ (row & 15)) * 8 + half * 4);
        uint2 p;
        p.x = f2bf(a0[j]) | ((unsigned int)f2bf(a1[j]) << 16);
        p.y = f2bf(a2[j]) | ((unsigned int)f2bf(a3[j]) << 16);
        *(uint2*)(lds + off) = p;
      }
      {
        int kq = kq0 + 16;
        int ch = kq >> 1, half = kq & 1;
        unsigned int off = (unsigned int)row * 128 + ((ch ^ (row & 15)) * 8 + half * 4);
        uint2 p;
        p.x = f2bf(b0[j]) | ((unsigned int)f2bf(b1[j]) << 16);
        p.y = f2bf(b2[j]) | ((unsigned int)f2bf(b3[j]) << 16);
        *(uint2*)(lds + off) = p;
      }
    }
  }
  __syncthreads();

  size_t bbase = ((size_t)n_blk * 32 + (size_t)k_blk * 4) * 4096;
#pragma unroll
  for (int i = 0; i < 4; i++) {
    int g = tid + i * 512;            // output chunk 0..2047
    int kcr = g >> 9;
    int c = g & 511;
    int row = c >> 2, koff = c & 3;
    int ch = kcr * 4 + koff;
    uint4 val = *(const uint4*)(lds + (unsigned int)row * 128 + (ch ^ (row & 15)) * 8);
    *(uint4*)(dst + bbase + (size_t)g * 8) = val;
  }
}

// ---------------- K1: router (blocks 0..255, 8 tokens each) ∪ transpose(w1,w3) -----------------
__global__ __launch_bounds__(512) void t13_router(
    const float* __restrict__ x, const float* __restrict__ gw,
    const float* __restrict__ w1, const float* __restrict__ w3,
    const float* __restrict__ w1s, const float* __restrict__ w3s,
    unsigned short* __restrict__ w1t, unsigned short* __restrict__ w3t,
    unsigned short* __restrict__ w1st, unsigned short* __restrict__ w3st,
    unsigned short* __restrict__ xbf,
    int* __restrict__ e0, int* __restrict__ e1,
    float* __restrict__ s0, float* __restrict__ s1) {
  __shared__ __align__(16) unsigned short lds[128 * 128];   // 32KB (transpose role)
  int b = blockIdx.x;
  if (b < 256) {
    // ---- router role: token = b*8 + (tid>>6), lane = tid&63 ----
    int lane = threadIdx.x & 63;
    int t = b * 8 + (threadIdx.x >> 6);
    const float4* xr4 = (const float4*)(x + (size_t)t * DIM);
    float4 xv[4];
#pragma unroll
    for (int i = 0; i < 4; i++) xv[i] = xr4[i * 64 + lane];

    ushort4* xb4 = (ushort4*)(xbf + (size_t)t * DIM);
#pragma unroll
    for (int i = 0; i < 4; i++) {
      ushort4 o;
      o.x = f2bf(xv[i].x); o.y = f2bf(xv[i].y); o.z = f2bf(xv[i].z); o.w = f2bf(xv[i].w);
      xb4[i * 64 + lane] = o;
    }
    if (t == 0) {        // zero pad row NTOK
      ushort4 zz; zz.x = zz.y = zz.z = zz.w = 0;
      ushort4* pb4 = (ushort4*)(xbf + (size_t)NTOK * DIM);
#pragma unroll
      for (int i = 0; i < 4; i++) pb4[i * 64 + lane] = zz;
    }

    float acc[NEXP];
#pragma unroll
    for (int e = 0; e < NEXP; e++) {
      const float4* g4 = (const float4*)(gw + (size_t)e * DIM);
      float a = 0.f;
#pragma unroll
      for (int i = 0; i < 4; i++) {
        float4 g = g4[i * 64 + lane];
        a += xv[i].x * g.x + xv[i].y * g.y + xv[i].z * g.z + xv[i].w * g.w;
      }
      acc[e] = a;
    }
#pragma unroll
    for (int e = 0; e < NEXP; e++) {
      float v = acc[e];
      for (int o = 32; o > 0; o >>= 1) v += __shfl_xor(v, o);
      acc[e] = v;
    }
    if (lane == 0) {
      float m = acc[0];
#pragma unroll
      for (int e = 1; e < NEXP; e++) m = fmaxf(m, acc[e]);
      float ex[NEXP]; float Z = 0.f;
#pragma unroll
      for (int e = 0; e < NEXP; e++) { ex[e] = __expf(acc[e] - m); Z += ex[e]; }
      float inv = 1.f / Z;
      float sc[NEXP];
#pragma unroll
      for (int e = 0; e < NEXP; e++) sc[e] = ex[e] * inv;
      int b0 = 0; float v0 = sc[0];
#pragma unroll
      for (int e = 1; e < NEXP; e++) if (sc[e] > v0) { v0 = sc[e]; b0 = e; }
      int b1 = -1; float v1 = -1.f;
#pragma unroll
      for (int e = 0; e < NEXP; e++) if (e != b0 && sc[e] > v1) { v1 = sc[e]; b1 = e; }
      e0[t] = b0; e1[t] = b1; s0[t] = v0; s1[t] = v1;
    }
  } else {
    // ---- transpose role: 18 slices x 64 blocks (w1:0-7, w3:8-15, w1s:16, w3s:17) ----
    int bb = b - 256;
    int slice = bb >> 6, s6 = bb & 63;
    int n_blk = s6 & 7, k_blk = s6 >> 3;
    const float* src; unsigned short* dst;
    if (slice < 8)       { src = w1 + (size_t)slice * MM;       dst = w1t + (size_t)slice * MM; }
    else if (slice < 16) { src = w3 + (size_t)(slice - 8) * MM; dst = w3t + (size_t)(slice - 8) * MM; }
    else if (slice == 16){ src = w1s; dst = w1st; }
    else                 { src = w3s; dst = w3st; }
    brick_transpose(src, dst, n_blk, k_blk, lds);
  }
}

// ---------------- deterministic grouped build: packed uint4 scan (128-row padding) -------------
__global__ __launch_bounds__(256) void build_groups(
    const int* __restrict__ e0, const int* __restrict__ e1,
    const float* __restrict__ s0, const float* __restrict__ s1,
    int* __restrict__ gtok, float* __restrict__ gsc, int* __restrict__ row_of,
    int* __restrict__ tile_e, int* __restrict__ tile_r0, int* __restrict__ ntiles,
    int* __restrict__ base8out) {
  __shared__ unsigned int wsum[4][4];
  __shared__ int offl[256][NEXP];
  __shared__ int lrl[256][NEXP];
  int t = threadIdx.x, lane = t & 63, wave = t >> 6;

  for (int i = t; i < ROWS_CAP; i += 256) { gtok[i] = NTOK; gsc[i] = 0.f; }  // pad -> zero row

  unsigned int pc[4] = {0, 0, 0, 0};
#pragma unroll
  for (int i = 0; i < 16; i++) {
    int ent = t * 16 + i;
    int tok = ent >> 1;
    int e = (ent & 1) ? e1[tok] : e0[tok];
    unsigned int add = 1u << ((e & 1) * 16);
    int c = e >> 1;
    if (c == 0) pc[0] += add; else if (c == 1) pc[1] += add;
    else if (c == 2) pc[2] += add; else pc[3] += add;
  }
  unsigned int incl[4] = {pc[0], pc[1], pc[2], pc[3]};
#pragma unroll
  for (int o = 1; o < 64; o <<= 1) {
    unsigned int u0 = __shfl_up(incl[0], o), u1 = __shfl_up(incl[1], o);
    unsigned int u2 = __shfl_up(incl[2], o), u3 = __shfl_up(incl[3], o);
    if (lane >= o) { incl[0] += u0; incl[1] += u1; incl[2] += u2; incl[3] += u3; }
  }
  if (lane == 63) { wsum[wave][0] = incl[0]; wsum[wave][1] = incl[1];
                    wsum[wave][2] = incl[2]; wsum[wave][3] = incl[3]; }
  __syncthreads();
  unsigned int T[4], pre[4] = {0, 0, 0, 0};
#pragma unroll
  for (int c = 0; c < 4; c++)
    T[c] = wsum[0][c] + wsum[1][c] + wsum[2][c] + wsum[3][c];
#pragma unroll
  for (int w = 0; w < 3; w++)
    if (wave > w) { pre[0] += wsum[w][0]; pre[1] += wsum[w][1];
                    pre[2] += wsum[w][2]; pre[3] += wsum[w][3]; }
  int base[NEXP + 1];
  {
    int b = 0;
#pragma unroll
    for (int e = 0; e < NEXP; e++) {
      int tot = (int)((T[e >> 1] >> ((e & 1) * 16)) & 0xFFFFu);
      base[e] = b; b += (tot + 127) & ~127;
    }
    base[NEXP] = b;
  }
#pragma unroll
  for (int e = 0; e < NEXP; e++) {
    unsigned int ex = (incl[e >> 1] + pre[e >> 1] - pc[e >> 1]);
    offl[t][e] = (int)((ex >> ((e & 1) * 16)) & 0xFFFFu);
    lrl[t][e] = 0;
  }
  if (t == 0) {
    int nt = 0;
#pragma unroll
    for (int e = 0; e < NEXP; e++) {
      int tot = (int)((T[e >> 1] >> ((e & 1) * 16)) & 0xFFFFu);
      int ntl = (tot + 127) >> 7;
      for (int i = 0; i < ntl; i++) { tile_e[nt] = e; tile_r0[nt] = base[e] + i * 128; nt++; }
    }
    for (int i = 0; i < NTOK / 128; i++) { tile_e[nt] = NEXP; tile_r0[nt] = base[NEXP] + i * 128; nt++; }
    *ntiles = nt;
    *base8out = base[NEXP];
  }
  __syncthreads();   // gtok/gsc clear complete before scatter

#pragma unroll
  for (int i = 0; i < 16; i++) {
    int ent = t * 16 + i;
    int tok = ent >> 1;
    int k = ent & 1;
    int e = k ? e1[tok] : e0[tok];
    float s = k ? s1[tok] : s0[tok];
    int pos = base[e] + offl[t][e] + lrl[t][e];
    lrl[t][e]++;
    gtok[pos] = tok; gsc[pos] = s; row_of[ent] = pos;
  }
  for (int i = t; i < NTOK; i += 256) { gtok[base[NEXP] + i] = i; gsc[base[NEXP] + i] = 1.0f; }
}

// ---------------- K3: gemm13 (blocks 0..511) ∪ transpose(w2,w2s) (blocks 512..1087) ------------
__global__ __launch_bounds__(512, 4) void gemm13_t2(
    const unsigned short* __restrict__ xbf,
    const unsigned short* __restrict__ W1, const unsigned short* __restrict__ W1s,
    const unsigned short* __restrict__ W3, const unsigned short* __restrict__ W3s,
    const float* __restrict__ w2, const float* __restrict__ w2s,
    unsigned short* __restrict__ w2t, unsigned short* __restrict__ w2st,
    unsigned short* __restrict__ H,
    const int* __restrict__ gtok, const float* __restrict__ gsc,
    const int* __restrict__ tile_e, const int* __restrict__ tile_r0,
    const int* __restrict__ ntiles) {
  __shared__ __align__(16) char smem[33280];   // union: 32KB transpose | 24.5KB gemm13
  int b = blockIdx.x;
  if (b >= 512) {
    // ---- transpose role: 9 slices x 64 blocks (w2:0-7, w2s:8) ----
    int bb = b - 512;
    int slice = bb >> 6, s6 = bb & 63;
    int n_blk = s6 & 7, k_blk = s6 >> 3;
    const float* src; unsigned short* dst;
    if (slice < 8) { src = w2 + (size_t)slice * MM; dst = w2t + (size_t)slice * MM; }
    else           { src = w2s; dst = w2st; }
    brick_transpose(src, dst, n_blk, k_blk, (unsigned short*)smem);
    return;
  }
  // ---- gemm13 role (R12 body): tile = b>>3, col-block = b&7 ----
  int ti = b >> 3;
  if (ti >= *ntiles) return;
  int e = tile_e[ti];
  int row0 = tile_r0[ti];
  int col0 = (b & 7) * 128;
  const unsigned short* B1 = (e < NEXP) ? (W1 + (size_t)e * MM) : W1s;
  const unsigned short* B3 = (e < NEXP) ? (W3 + (size_t)e * MM) : W3s;

  unsigned short* As  = (unsigned short*)smem;            // 8KB
  unsigned short* Bs1 = (unsigned short*)(smem + 8192);   // 8KB
  unsigned short* Bs3 = (unsigned short*)(smem + 16384);  // 8KB
  float* ss = (float*)(smem + 24576);                     // 512B

  int tid = threadIdx.x;
  int wave = tid >> 6, lane = tid & 63;
  int wrow = (wave & 3) * 32, wcol = (wave >> 2) * 64;

  if (tid < 128) ss[tid] = gsc[row0 + tid];   // synced by first K-loop barrier

  f32x4 acc1[2][4], acc3[2][4];
#pragma unroll
  for (int m = 0; m < 2; m++)
#pragma unroll
    for (int n = 0; n < 4; n++) { acc1[m][n] = f32x4{0.f,0.f,0.f,0.f}; acc3[m][n] = f32x4{0.f,0.f,0.f,0.f}; }

  int arow = tid >> 2, koff = (tid & 3) * 8;
  const unsigned short* ga  = xbf + (size_t)gtok[row0 + arow] * DIM + koff;
  const unsigned short* gb1 = B1 + ((size_t)(col0 >> 7) * 32) * 4096 + (size_t)tid * 8;
  const unsigned short* gb3 = B3 + ((size_t)(col0 >> 7) * 32) * 4096 + (size_t)tid * 8;
  unsigned short* lA  = As  + wave * 512;
  unsigned short* lB1 = Bs1 + wave * 512;
  unsigned short* lB3 = Bs3 + wave * 512;

  int kc = lane >> 4, rl = lane & 15;

  for (int k0 = 0; k0 < DIM; k0 += 32) {
    size_t boff = (size_t)(k0 >> 5) * 4096;
    gload_lds16(ga + k0, lA);
    gload_lds16(gb1 + boff, lB1);
    gload_lds16(gb3 + boff, lB3);
    __syncthreads();

    const bf16x8* Ap  = (const bf16x8*)As;
    const bf16x8* B1p = (const bf16x8*)Bs1;
    const bf16x8* B3p = (const bf16x8*)Bs3;
    bf16x8 af[2], b1f[4], b3f[4];
#pragma unroll
    for (int m = 0; m < 2; m++) af[m] = Ap[(wrow + m * 16 + rl) * 4 + kc];
#pragma unroll
    for (int n = 0; n < 4; n++) { b1f[n] = B1p[(wcol + n * 16 + rl) * 4 + kc];
                                  b3f[n] = B3p[(wcol + n * 16 + rl) * 4 + kc]; }
#pragma unroll
    for (int m = 0; m < 2; m++)
#pragma unroll
      for (int n = 0; n < 4; n++) {
        acc1[m][n] = __builtin_amdgcn_mfma_f32_16x16x32_bf16(af[m], b1f[n], acc1[m][n], 0, 0, 0);
        acc3[m][n] = __builtin_amdgcn_mfma_f32_16x16x32_bf16(af[m], b3f[n], acc3[m][n], 0, 0, 0);
      }
    __syncthreads();
  }

  int rj = lane >> 4, cl = lane & 15;
#pragma unroll
  for (int m = 0; m < 2; m++)
#pragma unroll
    for (int n = 0; n < 4; n++)
#pragma unroll
      for (int j = 0; j < 4; j++) {
        int lr = wrow + m * 16 + rj * 4 + j;
        float s = ss[lr];
        float a = s * acc1[m][n][j];
        float g = s * acc3[m][n][j];
        float si = a / (1.f + __expf(-a));
        H[(size_t)(row0 + lr) * DIM + (col0 + wcol + n * 16 + cl)] = f2bf(si * g);
      }
}

// ---------------- grouped GEMM: rout = H * W2_e (fp32 out); W2^T bricks ------------------------
__global__ __launch_bounds__(512, 4) void gemm2(
    const unsigned short* __restrict__ A, const unsigned short* __restrict__ W,
    const unsigned short* __restrict__ Wsh, float* __restrict__ C,
    const int* __restrict__ tile_e, const int* __restrict__ tile_r0,
    const int* __restrict__ ntiles) {
  if ((int)blockIdx.y >= *ntiles) return;
  int e = tile_e[blockIdx.y];
  int row0 = tile_r0[blockIdx.y];
  int col0 = blockIdx.x * 128;
  const unsigned short* B = (e < NEXP) ? (W + (size_t)e * MM) : Wsh;

  __shared__ __align__(16) unsigned short As[128 * 32];
  __shared__ __align__(16) unsigned short Bs[128 * 32];

  int tid = threadIdx.x;
  int wave = tid >> 6, lane = tid & 63;
  int wrow = (wave & 3) * 32, wcol = (wave >> 2) * 64;

  f32x4 acc[2][4];
#pragma unroll
  for (int m = 0; m < 2; m++)
#pragma unroll
    for (int n = 0; n < 4; n++) acc[m][n] = f32x4{0.f, 0.f, 0.f, 0.f};

  int arow = tid >> 2, koff = (tid & 3) * 8;
  const unsigned short* ga = A + (size_t)(row0 + arow) * DIM + koff;
  const unsigned short* gb = B + ((size_t)(col0 >> 7) * 32) * 4096 + (size_t)tid * 8;
  unsigned short* lA = As + wave * 512;
  unsigned short* lB = Bs + wave * 512;

  int kc = lane >> 4, rl = lane & 15;

  for (int k0 = 0; k0 < DIM; k0 += 32) {
    size_t boff = (size_t)(k0 >> 5) * 4096;
    gload_lds16(ga + k0, lA);
    gload_lds16(gb + boff, lB);
    __syncthreads();

    const bf16x8* Ap = (const bf16x8*)As;
    const bf16x8* Bp = (const bf16x8*)Bs;
    bf16x8 af[2], bfr[4];
#pragma unroll
    for (int m = 0; m < 2; m++) af[m] = Ap[(wrow + m * 16 + rl) * 4 + kc];
#pragma unroll
    for (int n = 0; n < 4; n++) bfr[n] = Bp[(wcol + n * 16 + rl) * 4 + kc];
#pragma unroll
    for (int m = 0; m < 2; m++)
#pragma unroll
      for (int n = 0; n < 4; n++)
        acc[m][n] = __builtin_amdgcn_mfma_f32_16x16x32_bf16(af[m], bfr[n], acc[m][n], 0, 0, 0);
    __syncthreads();
  }

  int rj = lane >> 4, cl = lane & 15;
#pragma unroll
  for (int m = 0; m < 2; m++)
#pragma unroll
    for (int n = 0; n < 4; n++)
#pragma unroll
      for (int j = 0; j < 4; j++) {
        int r = row0 + wrow + m * 16 + rj * 4 + j;
        int c = col0 + wcol + n * 16 + cl;
        C[(size_t)r * DIM + c] = acc[m][n][j];
      }
}

// ---------------- combine: out[t] = rout[r0] + rout[r1] + rout[shared] -------------------------
__global__ __launch_bounds__(256) void combine(const float* __restrict__ rout,
                                               const int* __restrict__ row_of,
                                               const int* __restrict__ base8,
                                               float* __restrict__ out) {
  int t = blockIdx.x;
  int c = threadIdx.x * 4;
  int r0 = row_of[2 * t], r1 = row_of[2 * t + 1];
  int rs = *base8 + t;
  float4 v0 = *(const float4*)(rout + (size_t)r0 * DIM + c);
  float4 v1 = *(const float4*)(rout + (size_t)r1 * DIM + c);
  float4 v2 = *(const float4*)(rout + (size_t)rs * DIM + c);
  float4 o;
  o.x = v0.x + v1.x + v2.x;
  o.y = v0.y + v1.y + v2.y;
  o.z = v0.z + v1.z + v2.z;
  o.w = v0.w + v1.w + v2.w;
  *(float4*)(out + (size_t)t * DIM + c) = o;
}

extern "C" void kernel_launch(void* const* d_in, const int* in_sizes, int n_in,
                              void* d_out, int out_size, void* d_ws, size_t ws_size,
                              hipStream_t stream) {
  const float* x   = (const float*)d_in[0];
  const float* gw  = (const float*)d_in[1];
  const float* w1  = (const float*)d_in[2];
  const float* w2  = (const float*)d_in[3];
  const float* w3  = (const float*)d_in[4];
  const float* w1s = (const float*)d_in[5];
  const float* w2s = (const float*)d_in[6];
  const float* w3s = (const float*)d_in[7];
  float* out = (float*)d_out;
  char* ws = (char*)d_ws;

  const size_t MB = 1ull << 20;
  unsigned short* w1t  = (unsigned short*)(ws + 0 * MB);    // 16MB [8] brick-layout W1^T
  unsigned short* w3t  = (unsigned short*)(ws + 16 * MB);   // 16MB
  unsigned short* w2t  = (unsigned short*)(ws + 32 * MB);   // 16MB
  unsigned short* w1st = (unsigned short*)(ws + 48 * MB);   // 2MB
  unsigned short* w3st = (unsigned short*)(ws + 50 * MB);   // 2MB
  unsigned short* w2st = (unsigned short*)(ws + 52 * MB);   // 2MB
  unsigned short* xbf  = (unsigned short*)(ws + 54 * MB);   // 4MB+  [NTOK+1][1024] bf16
  unsigned short* hbuf = (unsigned short*)(ws + 60 * MB);   // 16MB [8192][1024] bf16
  float* rout = (float*)(ws + 76 * MB);                     // 32MB [8192][1024] fp32
  char* meta = ws + 108 * MB;
  int*   e0p    = (int*)meta;
  int*   e1p    = e0p + NTOK;
  float* s0p    = (float*)(e1p + NTOK);
  float* s1p    = s0p + NTOK;
  int*   gtok   = (int*)(s1p + NTOK);
  float* gsc    = (float*)(gtok + ROWS_CAP);
  int*   row_of = (int*)(gsc + ROWS_CAP);
  int*   tile_e = row_of + NENT;
  int*   tile_r0= tile_e + MAX_TILES;
  int*   ntiles = tile_r0 + MAX_TILES;
  int*   base8  = ntiles + 1;

  // K1: router (256 blocks) ∪ transpose w1/w3/w1s/w3s (1152 blocks)
  t13_router<<<256 + 18 * 64, 512, 0, stream>>>(
      x, gw, w1, w3, w1s, w3s, w1t, w3t, w1st, w3st, xbf, e0p, e1p, s0p, s1p);
  // K2: deterministic group build
  build_groups<<<1, 256, 0, stream>>>(e0p, e1p, s0p, s1p, gtok, gsc, row_of,
                                      tile_e, tile_r0, ntiles, base8);
  // K3: gemm13 (512 blocks) ∪ transpose w2/w2s (576 blocks)
  gemm13_t2<<<512 + 9 * 64, 512, 0, stream>>>(
      xbf, w1t, w1st, w3t, w3st, w2, w2s, w2t, w2st, hbuf,
      gtok, gsc, tile_e, tile_r0, ntiles);
  // K4: gemm2
  dim3 gg(8, MAX_TILES);
  gemm2<<<gg, 512, 0, stream>>>(hbuf, w2t, w2st, rout, tile_e, tile_r0, ntiles);
  // K5: combine
  combine<<<NTOK, 256, 0, stream>>>(rout, row_of, base8, out);
}

// Round 14
// 102.609 us; speedup vs baseline: 1.4133x; 1.0797x over previous
//
#include <hip/hip_runtime.h>
#include <hip/hip_bf16.h>

// MoE top-2 + shared expert, bf16 MFMA path. Round 14.
// vs R13 (110.8us): (1) GEMM fragment-read bank de-conflict — reads use
// kc' = (kc + (row>>1))&3 (2-way = free, vs 8-way = 2.94x); inverse
// permutation baked into the BRICK writer (B side) and per-lane gload
// source (A side). (2) rout fp32 -> bf16 (gemm2 epilogue cast; combine
// reads bf16): -24MB tail traffic. Structure = R13 (co-scheduled K1/K3).

#define DIM 1024
#define NTOK 2048
#define NEXP 8
#define NENT 4096          // NTOK * 2
#define ROWS_CAP 8192      // padded grouped rows upper bound
#define MAX_TILES 64
#define MM (DIM * DIM)

typedef float f32x4 __attribute__((ext_vector_type(4)));
typedef __bf16 bf16x8 __attribute__((ext_vector_type(8)));

__device__ __forceinline__ unsigned short f2bf(float f) {
  unsigned int u = __builtin_bit_cast(unsigned int, f);
  unsigned int r = u + 0x7FFFu + ((u >> 16) & 1u);   // RNE
  return (unsigned short)(r >> 16);
}
__device__ __forceinline__ float bf2f(unsigned short h) {
  unsigned int u = ((unsigned int)h) << 16;
  return __builtin_bit_cast(float, u);
}
__device__ __forceinline__ void gload_lds16(const unsigned short* g, unsigned short* l) {
  __builtin_amdgcn_global_load_lds((__attribute__((address_space(1))) const void*)g,
                                   (__attribute__((address_space(3))) void*)l, 16, 0, 0);
}

// ---------------- brick transpose: 128n x 128k tile -> 4 bricks (8KB each) ---------------------
// Brick position (row, p) holds data k-chunk koff = (p - (row>>1))&3  [read-deconflict
// permutation]; GEMM reads fragment at position (kc + (row>>1))&3 to get chunk kc.
__device__ __forceinline__ void brick_transpose(const float* __restrict__ src,
                                                unsigned short* __restrict__ dst,
                                                int n_blk, int k_blk,
                                                unsigned short* lds) {
  int c0 = n_blk * 128, r0 = k_blk * 128;
  int tid = threadIdx.x;
  int q = tid & 31;                   // n-quad (n = 4q..4q+3)
  int kq0 = tid >> 5;                 // k-quad 0..15; second pass at +16

  const float* sp0 = src + (size_t)(r0 + kq0 * 4) * DIM + c0 + q * 4;
  const float* sp1 = sp0 + (size_t)64 * DIM;     // kq0+16
  float4 v0 = *(const float4*)(sp0 + 0 * DIM);
  float4 v1 = *(const float4*)(sp0 + 1 * DIM);
  float4 v2 = *(const float4*)(sp0 + 2 * DIM);
  float4 v3 = *(const float4*)(sp0 + 3 * DIM);
  float4 v4 = *(const float4*)(sp1 + 0 * DIM);
  float4 v5 = *(const float4*)(sp1 + 1 * DIM);
  float4 v6 = *(const float4*)(sp1 + 2 * DIM);
  float4 v7 = *(const float4*)(sp1 + 3 * DIM);
  {
    float a0[4] = {v0.x, v0.y, v0.z, v0.w};
    float a1[4] = {v1.x, v1.y, v1.z, v1.w};
    float a2[4] = {v2.x, v2.y, v2.z, v2.w};
    float a3[4] = {v3.x, v3.y, v3.z, v3.w};
    float b0[4] = {v4.x, v4.y, v4.z, v4.w};
    float b1[4] = {v5.x, v5.y, v5.z, v5.w};
    float b2[4] = {v6.x, v6.y, v6.z, v6.w};
    float b3[4] = {v7.x, v7.y, v7.z, v7.w};
#pragma unroll
    for (int j = 0; j < 4; j++) {
      int row = q * 4 + j;
      {
        int kq = kq0;
        int ch = kq >> 1, half = kq & 1;
        unsigned int off = (unsigned int)row * 128 + ((ch ^ (row & 15)) * 8 + half * 4);
        uint2 p;
        p.x = f2bf(a0[j]) | ((unsigned int)f2bf(a1[j]) << 16);
        p.y = f2bf(a2[j]) | ((unsigned int)f2bf(a3[j]) << 16);
        *(uint2*)(lds + off) = p;
      }
      {
        int kq = kq0 + 16;
        int ch = kq >> 1, half = kq & 1;
        unsigned int off = (unsigned int)row * 128 + ((ch ^ (row & 15)) * 8 + half * 4);
        uint2 p;
        p.x = f2bf(b0[j]) | ((unsigned int)f2bf(b1[j]) << 16);
        p.y = f2bf(b2[j]) | ((unsigned int)f2bf(b3[j]) << 16);
        *(uint2*)(lds + off) = p;
      }
    }
  }
  __syncthreads();

  size_t bbase = ((size_t)n_blk * 32 + (size_t)k_blk * 4) * 4096;
#pragma unroll
  for (int i = 0; i < 4; i++) {
    int g = tid + i * 512;            // output chunk 0..2047
    int kcr = g >> 9;
    int c = g & 511;
    int row = c >> 2, p = c & 3;
    int koff = (p - (row >> 1)) & 3;  // data chunk stored at position p
    int ch = kcr * 4 + koff;
    uint4 val = *(const uint4*)(lds + (unsigned int)row * 128 + (ch ^ (row & 15)) * 8);
    *(uint4*)(dst + bbase + (size_t)g * 8) = val;
  }
}

// ---------------- K1: router (blocks 0..255, 8 tokens each) ∪ transpose(w1,w3) -----------------
__global__ __launch_bounds__(512) void t13_router(
    const float* __restrict__ x, const float* __restrict__ gw,
    const float* __restrict__ w1, const float* __restrict__ w3,
    const float* __restrict__ w1s, const float* __restrict__ w3s,
    unsigned short* __restrict__ w1t, unsigned short* __restrict__ w3t,
    unsigned short* __restrict__ w1st, unsigned short* __restrict__ w3st,
    unsigned short* __restrict__ xbf,
    int* __restrict__ e0, int* __restrict__ e1,
    float* __restrict__ s0, float* __restrict__ s1) {
  __shared__ __align__(16) unsigned short lds[128 * 128];   // 32KB (transpose role)
  int b = blockIdx.x;
  if (b < 256) {
    int lane = threadIdx.x & 63;
    int t = b * 8 + (threadIdx.x >> 6);
    const float4* xr4 = (const float4*)(x + (size_t)t * DIM);
    float4 xv[4];
#pragma unroll
    for (int i = 0; i < 4; i++) xv[i] = xr4[i * 64 + lane];

    ushort4* xb4 = (ushort4*)(xbf + (size_t)t * DIM);
#pragma unroll
    for (int i = 0; i < 4; i++) {
      ushort4 o;
      o.x = f2bf(xv[i].x); o.y = f2bf(xv[i].y); o.z = f2bf(xv[i].z); o.w = f2bf(xv[i].w);
      xb4[i * 64 + lane] = o;
    }
    if (t == 0) {        // zero pad row NTOK
      ushort4 zz; zz.x = zz.y = zz.z = zz.w = 0;
      ushort4* pb4 = (ushort4*)(xbf + (size_t)NTOK * DIM);
#pragma unroll
      for (int i = 0; i < 4; i++) pb4[i * 64 + lane] = zz;
    }

    float acc[NEXP];
#pragma unroll
    for (int e = 0; e < NEXP; e++) {
      const float4* g4 = (const float4*)(gw + (size_t)e * DIM);
      float a = 0.f;
#pragma unroll
      for (int i = 0; i < 4; i++) {
        float4 g = g4[i * 64 + lane];
        a += xv[i].x * g.x + xv[i].y * g.y + xv[i].z * g.z + xv[i].w * g.w;
      }
      acc[e] = a;
    }
#pragma unroll
    for (int e = 0; e < NEXP; e++) {
      float v = acc[e];
      for (int o = 32; o > 0; o >>= 1) v += __shfl_xor(v, o);
      acc[e] = v;
    }
    if (lane == 0) {
      float m = acc[0];
#pragma unroll
      for (int e = 1; e < NEXP; e++) m = fmaxf(m, acc[e]);
      float ex[NEXP]; float Z = 0.f;
#pragma unroll
      for (int e = 0; e < NEXP; e++) { ex[e] = __expf(acc[e] - m); Z += ex[e]; }
      float inv = 1.f / Z;
      float sc[NEXP];
#pragma unroll
      for (int e = 0; e < NEXP; e++) sc[e] = ex[e] * inv;
      int b0 = 0; float v0 = sc[0];
#pragma unroll
      for (int e = 1; e < NEXP; e++) if (sc[e] > v0) { v0 = sc[e]; b0 = e; }
      int b1 = -1; float v1 = -1.f;
#pragma unroll
      for (int e = 0; e < NEXP; e++) if (e != b0 && sc[e] > v1) { v1 = sc[e]; b1 = e; }
      e0[t] = b0; e1[t] = b1; s0[t] = v0; s1[t] = v1;
    }
  } else {
    int bb = b - 256;
    int slice = bb >> 6, s6 = bb & 63;
    int n_blk = s6 & 7, k_blk = s6 >> 3;
    const float* src; unsigned short* dst;
    if (slice < 8)       { src = w1 + (size_t)slice * MM;       dst = w1t + (size_t)slice * MM; }
    else if (slice < 16) { src = w3 + (size_t)(slice - 8) * MM; dst = w3t + (size_t)(slice - 8) * MM; }
    else if (slice == 16){ src = w1s; dst = w1st; }
    else                 { src = w3s; dst = w3st; }
    brick_transpose(src, dst, n_blk, k_blk, lds);
  }
}

// ---------------- deterministic grouped build: packed uint4 scan (128-row padding) -------------
__global__ __launch_bounds__(256) void build_groups(
    const int* __restrict__ e0, const int* __restrict__ e1,
    const float* __restrict__ s0, const float* __restrict__ s1,
    int* __restrict__ gtok, float* __restrict__ gsc, int* __restrict__ row_of,
    int* __restrict__ tile_e, int* __restrict__ tile_r0, int* __restrict__ ntiles,
    int* __restrict__ base8out) {
  __shared__ unsigned int wsum[4][4];
  __shared__ int offl[256][NEXP];
  __shared__ int lrl[256][NEXP];
  int t = threadIdx.x, lane = t & 63, wave = t >> 6;

  for (int i = t; i < ROWS_CAP; i += 256) { gtok[i] = NTOK; gsc[i] = 0.f; }  // pad -> zero row

  unsigned int pc[4] = {0, 0, 0, 0};
#pragma unroll
  for (int i = 0; i < 16; i++) {
    int ent = t * 16 + i;
    int tok = ent >> 1;
    int e = (ent & 1) ? e1[tok] : e0[tok];
    unsigned int add = 1u << ((e & 1) * 16);
    int c = e >> 1;
    if (c == 0) pc[0] += add; else if (c == 1) pc[1] += add;
    else if (c == 2) pc[2] += add; else pc[3] += add;
  }
  unsigned int incl[4] = {pc[0], pc[1], pc[2], pc[3]};
#pragma unroll
  for (int o = 1; o < 64; o <<= 1) {
    unsigned int u0 = __shfl_up(incl[0], o), u1 = __shfl_up(incl[1], o);
    unsigned int u2 = __shfl_up(incl[2], o), u3 = __shfl_up(incl[3], o);
    if (lane >= o) { incl[0] += u0; incl[1] += u1; incl[2] += u2; incl[3] += u3; }
  }
  if (lane == 63) { wsum[wave][0] = incl[0]; wsum[wave][1] = incl[1];
                    wsum[wave][2] = incl[2]; wsum[wave][3] = incl[3]; }
  __syncthreads();
  unsigned int T[4], pre[4] = {0, 0, 0, 0};
#pragma unroll
  for (int c = 0; c < 4; c++)
    T[c] = wsum[0][c] + wsum[1][c] + wsum[2][c] + wsum[3][c];
#pragma unroll
  for (int w = 0; w < 3; w++)
    if (wave > w) { pre[0] += wsum[w][0]; pre[1] += wsum[w][1];
                    pre[2] += wsum[w][2]; pre[3] += wsum[w][3]; }
  int base[NEXP + 1];
  {
    int b = 0;
#pragma unroll
    for (int e = 0; e < NEXP; e++) {
      int tot = (int)((T[e >> 1] >> ((e & 1) * 16)) & 0xFFFFu);
      base[e] = b; b += (tot + 127) & ~127;
    }
    base[NEXP] = b;
  }
#pragma unroll
  for (int e = 0; e < NEXP; e++) {
    unsigned int ex = (incl[e >> 1] + pre[e >> 1] - pc[e >> 1]);
    offl[t][e] = (int)((ex >> ((e & 1) * 16)) & 0xFFFFu);
    lrl[t][e] = 0;
  }
  if (t == 0) {
    int nt = 0;
#pragma unroll
    for (int e = 0; e < NEXP; e++) {
      int tot = (int)((T[e >> 1] >> ((e & 1) * 16)) & 0xFFFFu);
      int ntl = (tot + 127) >> 7;
      for (int i = 0; i < ntl; i++) { tile_e[nt] = e; tile_r0[nt] = base[e] + i * 128; nt++; }
    }
    for (int i = 0; i < NTOK / 128; i++) { tile_e[nt] = NEXP; tile_r0[nt] = base[NEXP] + i * 128; nt++; }
    *ntiles = nt;
    *base8out = base[NEXP];
  }
  __syncthreads();   // gtok/gsc clear complete before scatter

#pragma unroll
  for (int i = 0; i < 16; i++) {
    int ent = t * 16 + i;
    int tok = ent >> 1;
    int k = ent & 1;
    int e = k ? e1[tok] : e0[tok];
    float s = k ? s1[tok] : s0[tok];
    int pos = base[e] + offl[t][e] + lrl[t][e];
    lrl[t][e]++;
    gtok[pos] = tok; gsc[pos] = s; row_of[ent] = pos;
  }
  for (int i = t; i < NTOK; i += 256) { gtok[base[NEXP] + i] = i; gsc[base[NEXP] + i] = 1.0f; }
}

// ---------------- K3: gemm13 (blocks 0..511) ∪ transpose(w2,w2s) (blocks 512..1087) ------------
__global__ __launch_bounds__(512, 4) void gemm13_t2(
    const unsigned short* __restrict__ xbf,
    const unsigned short* __restrict__ W1, const unsigned short* __restrict__ W1s,
    const unsigned short* __restrict__ W3, const unsigned short* __restrict__ W3s,
    const float* __restrict__ w2, const float* __restrict__ w2s,
    unsigned short* __restrict__ w2t, unsigned short* __restrict__ w2st,
    unsigned short* __restrict__ H,
    const int* __restrict__ gtok, const float* __restrict__ gsc,
    const int* __restrict__ tile_e, const int* __restrict__ tile_r0,
    const int* __restrict__ ntiles) {
  __shared__ __align__(16) char smem[33280];   // union: 32KB transpose | 24.5KB gemm13
  int b = blockIdx.x;
  if (b >= 512) {
    int bb = b - 512;
    int slice = bb >> 6, s6 = bb & 63;
    int n_blk = s6 & 7, k_blk = s6 >> 3;
    const float* src; unsigned short* dst;
    if (slice < 8) { src = w2 + (size_t)slice * MM; dst = w2t + (size_t)slice * MM; }
    else           { src = w2s; dst = w2st; }
    brick_transpose(src, dst, n_blk, k_blk, (unsigned short*)smem);
    return;
  }
  int ti = b >> 3;
  if (ti >= *ntiles) return;
  int e = tile_e[ti];
  int row0 = tile_r0[ti];
  int col0 = (b & 7) * 128;
  const unsigned short* B1 = (e < NEXP) ? (W1 + (size_t)e * MM) : W1s;
  const unsigned short* B3 = (e < NEXP) ? (W3 + (size_t)e * MM) : W3s;

  unsigned short* As  = (unsigned short*)smem;            // 8KB
  unsigned short* Bs1 = (unsigned short*)(smem + 8192);   // 8KB
  unsigned short* Bs3 = (unsigned short*)(smem + 16384);  // 8KB
  float* ss = (float*)(smem + 24576);                     // 512B

  int tid = threadIdx.x;
  int wave = tid >> 6, lane = tid & 63;
  int wrow = (wave & 3) * 32, wcol = (wave >> 2) * 64;

  if (tid < 128) ss[tid] = gsc[row0 + tid];   // synced by first K-loop barrier

  f32x4 acc1[2][4], acc3[2][4];
#pragma unroll
  for (int m = 0; m < 2; m++)
#pragma unroll
    for (int n = 0; n < 4; n++) { acc1[m][n] = f32x4{0.f,0.f,0.f,0.f}; acc3[m][n] = f32x4{0.f,0.f,0.f,0.f}; }

  // A: per-lane gather; LDS position p=tid&3 of row tid>>2 holds data chunk (p-(row>>1))&3
  int arow = tid >> 2;
  int akoff = (((tid & 3) - (arow >> 1)) & 3) * 8;
  const unsigned short* ga  = xbf + (size_t)gtok[row0 + arow] * DIM + akoff;
  // B: linear brick read (permutation baked into brick format)
  const unsigned short* gb1 = B1 + ((size_t)(col0 >> 7) * 32) * 4096 + (size_t)tid * 8;
  const unsigned short* gb3 = B3 + ((size_t)(col0 >> 7) * 32) * 4096 + (size_t)tid * 8;
  unsigned short* lA  = As  + wave * 512;
  unsigned short* lB1 = Bs1 + wave * 512;
  unsigned short* lB3 = Bs3 + wave * 512;

  int kc = lane >> 4, rl = lane & 15;

  for (int k0 = 0; k0 < DIM; k0 += 32) {
    size_t boff = (size_t)(k0 >> 5) * 4096;
    gload_lds16(ga + k0, lA);
    gload_lds16(gb1 + boff, lB1);
    gload_lds16(gb3 + boff, lB3);
    __syncthreads();

    const bf16x8* Ap  = (const bf16x8*)As;
    const bf16x8* B1p = (const bf16x8*)Bs1;
    const bf16x8* B3p = (const bf16x8*)Bs3;
    bf16x8 af[2], b1f[4], b3f[4];
#pragma unroll
    for (int m = 0; m < 2; m++) {
      int row = wrow + m * 16 + rl;
      af[m] = Ap[row * 4 + ((kc + (row >> 1)) & 3)];
    }
#pragma unroll
    for (int n = 0; n < 4; n++) {
      int row = wcol + n * 16 + rl;
      int p = row * 4 + ((kc + (row >> 1)) & 3);
      b1f[n] = B1p[p];
      b3f[n] = B3p[p];
    }
#pragma unroll
    for (int m = 0; m < 2; m++)
#pragma unroll
      for (int n = 0; n < 4; n++) {
        acc1[m][n] = __builtin_amdgcn_mfma_f32_16x16x32_bf16(af[m], b1f[n], acc1[m][n], 0, 0, 0);
        acc3[m][n] = __builtin_amdgcn_mfma_f32_16x16x32_bf16(af[m], b3f[n], acc3[m][n], 0, 0, 0);
      }
    __syncthreads();
  }

  int rj = lane >> 4, cl = lane & 15;
#pragma unroll
  for (int m = 0; m < 2; m++)
#pragma unroll
    for (int n = 0; n < 4; n++)
#pragma unroll
      for (int j = 0; j < 4; j++) {
        int lr = wrow + m * 16 + rj * 4 + j;
        float s = ss[lr];
        float a = s * acc1[m][n][j];
        float g = s * acc3[m][n][j];
        float si = a / (1.f + __expf(-a));
        H[(size_t)(row0 + lr) * DIM + (col0 + wcol + n * 16 + cl)] = f2bf(si * g);
      }
}

// ---------------- grouped GEMM: routb = H * W2_e (bf16 out); W2^T bricks -----------------------
__global__ __launch_bounds__(512, 4) void gemm2(
    const unsigned short* __restrict__ A, const unsigned short* __restrict__ W,
    const unsigned short* __restrict__ Wsh, unsigned short* __restrict__ C,
    const int* __restrict__ tile_e, const int* __restrict__ tile_r0,
    const int* __restrict__ ntiles) {
  if ((int)blockIdx.y >= *ntiles) return;
  int e = tile_e[blockIdx.y];
  int row0 = tile_r0[blockIdx.y];
  int col0 = blockIdx.x * 128;
  const unsigned short* B = (e < NEXP) ? (W + (size_t)e * MM) : Wsh;

  __shared__ __align__(16) unsigned short As[128 * 32];
  __shared__ __align__(16) unsigned short Bs[128 * 32];

  int tid = threadIdx.x;
  int wave = tid >> 6, lane = tid & 63;
  int wrow = (wave & 3) * 32, wcol = (wave >> 2) * 64;

  f32x4 acc[2][4];
#pragma unroll
  for (int m = 0; m < 2; m++)
#pragma unroll
    for (int n = 0; n < 4; n++) acc[m][n] = f32x4{0.f, 0.f, 0.f, 0.f};

  int arow = tid >> 2;
  int akoff = (((tid & 3) - (arow >> 1)) & 3) * 8;
  const unsigned short* ga = A + (size_t)(row0 + arow) * DIM + akoff;
  const unsigned short* gb = B + ((size_t)(col0 >> 7) * 32) * 4096 + (size_t)tid * 8;
  unsigned short* lA = As + wave * 512;
  unsigned short* lB = Bs + wave * 512;

  int kc = lane >> 4, rl = lane & 15;

  for (int k0 = 0; k0 < DIM; k0 += 32) {
    size_t boff = (size_t)(k0 >> 5) * 4096;
    gload_lds16(ga + k0, lA);
    gload_lds16(gb + boff, lB);
    __syncthreads();

    const bf16x8* Ap = (const bf16x8*)As;
    const bf16x8* Bp = (const bf16x8*)Bs;
    bf16x8 af[2], bfr[4];
#pragma unroll
    for (int m = 0; m < 2; m++) {
      int row = wrow + m * 16 + rl;
      af[m] = Ap[row * 4 + ((kc + (row >> 1)) & 3)];
    }
#pragma unroll
    for (int n = 0; n < 4; n++) {
      int row = wcol + n * 16 + rl;
      bfr[n] = Bp[row * 4 + ((kc + (row >> 1)) & 3)];
    }
#pragma unroll
    for (int m = 0; m < 2; m++)
#pragma unroll
      for (int n = 0; n < 4; n++)
        acc[m][n] = __builtin_amdgcn_mfma_f32_16x16x32_bf16(af[m], bfr[n], acc[m][n], 0, 0, 0);
    __syncthreads();
  }

  int rj = lane >> 4, cl = lane & 15;
#pragma unroll
  for (int m = 0; m < 2; m++)
#pragma unroll
    for (int n = 0; n < 4; n++)
#pragma unroll
      for (int j = 0; j < 4; j++) {
        int r = row0 + wrow + m * 16 + rj * 4 + j;
        int c = col0 + wcol + n * 16 + cl;
        C[(size_t)r * DIM + c] = f2bf(acc[m][n][j]);
      }
}

// ---------------- combine: out[t] = routb[r0] + routb[r1] + routb[shared] (bf16 in) ------------
__global__ __launch_bounds__(256) void combine(const unsigned short* __restrict__ routb,
                                               const int* __restrict__ row_of,
                                               const int* __restrict__ base8,
                                               float* __restrict__ out) {
  int t = blockIdx.x;
  int c = threadIdx.x * 4;
  int r0 = row_of[2 * t], r1 = row_of[2 * t + 1];
  int rs = *base8 + t;
  ushort4 v0 = *(const ushort4*)(routb + (size_t)r0 * DIM + c);
  ushort4 v1 = *(const ushort4*)(routb + (size_t)r1 * DIM + c);
  ushort4 v2 = *(const ushort4*)(routb + (size_t)rs * DIM + c);
  float4 o;
  o.x = bf2f(v0.x) + bf2f(v1.x) + bf2f(v2.x);
  o.y = bf2f(v0.y) + bf2f(v1.y) + bf2f(v2.y);
  o.z = bf2f(v0.z) + bf2f(v1.z) + bf2f(v2.z);
  o.w = bf2f(v0.w) + bf2f(v1.w) + bf2f(v2.w);
  *(float4*)(out + (size_t)t * DIM + c) = o;
}

extern "C" void kernel_launch(void* const* d_in, const int* in_sizes, int n_in,
                              void* d_out, int out_size, void* d_ws, size_t ws_size,
                              hipStream_t stream) {
  const float* x   = (const float*)d_in[0];
  const float* gw  = (const float*)d_in[1];
  const float* w1  = (const float*)d_in[2];
  const float* w2  = (const float*)d_in[3];
  const float* w3  = (const float*)d_in[4];
  const float* w1s = (const float*)d_in[5];
  const float* w2s = (const float*)d_in[6];
  const float* w3s = (const float*)d_in[7];
  float* out = (float*)d_out;
  char* ws = (char*)d_ws;

  const size_t MB = 1ull << 20;
  unsigned short* w1t  = (unsigned short*)(ws + 0 * MB);    // 16MB [8] brick-layout W1^T
  unsigned short* w3t  = (unsigned short*)(ws + 16 * MB);   // 16MB
  unsigned short* w2t  = (unsigned short*)(ws + 32 * MB);   // 16MB
  unsigned short* w1st = (unsigned short*)(ws + 48 * MB);   // 2MB
  unsigned short* w3st = (unsigned short*)(ws + 50 * MB);   // 2MB
  unsigned short* w2st = (unsigned short*)(ws + 52 * MB);   // 2MB
  unsigned short* xbf  = (unsigned short*)(ws + 54 * MB);   // 4MB+  [NTOK+1][1024] bf16
  unsigned short* hbuf = (unsigned short*)(ws + 60 * MB);   // 16MB [8192][1024] bf16
  unsigned short* routb= (unsigned short*)(ws + 76 * MB);   // 16MB [8192][1024] bf16
  char* meta = ws + 108 * MB;
  int*   e0p    = (int*)meta;
  int*   e1p    = e0p + NTOK;
  float* s0p    = (float*)(e1p + NTOK);
  float* s1p    = s0p + NTOK;
  int*   gtok   = (int*)(s1p + NTOK);
  float* gsc    = (float*)(gtok + ROWS_CAP);
  int*   row_of = (int*)(gsc + ROWS_CAP);
  int*   tile_e = row_of + NENT;
  int*   tile_r0= tile_e + MAX_TILES;
  int*   ntiles = tile_r0 + MAX_TILES;
  int*   base8  = ntiles + 1;

  // K1: router (256 blocks) ∪ transpose w1/w3/w1s/w3s (1152 blocks)
  t13_router<<<256 + 18 * 64, 512, 0, stream>>>(
      x, gw, w1, w3, w1s, w3s, w1t, w3t, w1st, w3st, xbf, e0p, e1p, s0p, s1p);
  // K2: deterministic group build
  build_groups<<<1, 256, 0, stream>>>(e0p, e1p, s0p, s1p, gtok, gsc, row_of,
                                      tile_e, tile_r0, ntiles, base8);
  // K3: gemm13 (512 blocks) ∪ transpose w2/w2s (576 blocks)
  gemm13_t2<<<512 + 9 * 64, 512, 0, stream>>>(
      xbf, w1t, w1st, w3t, w3st, w2, w2s, w2t, w2st, hbuf,
      gtok, gsc, tile_e, tile_r0, ntiles);
  // K4: gemm2 (bf16 out)
  dim3 gg(8, MAX_TILES);
  gemm2<<<gg, 512, 0, stream>>>(hbuf, w2t, w2st, routb, tile_e, tile_r0, ntiles);
  // K5: combine
  combine<<<NTOK, 256, 0, stream>>>(routb, row_of, base8, out);
}

// Round 15
// 95.784 us; speedup vs baseline: 1.5140x; 1.0713x over previous
//
#include <hip/hip_runtime.h>
#include <hip/hip_bf16.h>

// MoE top-2 + shared expert, bf16 MFMA path. Round 15.
// vs R14 (102.6us): GEMM K-loop unrolled to BK=64 — two 32-k planes per
// buffer (bricks consumed pairwise), barriers halved (64 -> 32 per block),
// each vmcnt-drain amortized over 2x MFMA. gemm13 waves reshaped to 64x32
// (m-heavy: B-frag reads are the duplicated side with dual B) -> LDS frag
// traffic 80->64KB per 32k. gemm2 same BK=64. R14's de-conflict permutation
// and brick layout preserved. K1/build/transpose/combine unchanged.

#define DIM 1024
#define NTOK 2048
#define NEXP 8
#define NENT 4096          // NTOK * 2
#define ROWS_CAP 8192      // padded grouped rows upper bound
#define MAX_TILES 64
#define MM (DIM * DIM)

typedef float f32x4 __attribute__((ext_vector_type(4)));
typedef __bf16 bf16x8 __attribute__((ext_vector_type(8)));

__device__ __forceinline__ unsigned short f2bf(float f) {
  unsigned int u = __builtin_bit_cast(unsigned int, f);
  unsigned int r = u + 0x7FFFu + ((u >> 16) & 1u);   // RNE
  return (unsigned short)(r >> 16);
}
__device__ __forceinline__ float bf2f(unsigned short h) {
  unsigned int u = ((unsigned int)h) << 16;
  return __builtin_bit_cast(float, u);
}
__device__ __forceinline__ void gload_lds16(const unsigned short* g, unsigned short* l) {
  __builtin_amdgcn_global_load_lds((__attribute__((address_space(1))) const void*)g,
                                   (__attribute__((address_space(3))) void*)l, 16, 0, 0);
}

// ---------------- brick transpose (R14-verified): 128n x 128k tile -> 4 bricks -----------------
// Brick position (row, p) holds data k-chunk (p - (row>>1))&3; GEMM reads chunk kc at
// position (kc + (row>>1))&3. LDS staging swizzled ch^=(row&15).
__device__ __forceinline__ void brick_transpose(const float* __restrict__ src,
                                                unsigned short* __restrict__ dst,
                                                int n_blk, int k_blk,
                                                unsigned short* lds) {
  int c0 = n_blk * 128, r0 = k_blk * 128;
  int tid = threadIdx.x;
  int q = tid & 31;
  int kq0 = tid >> 5;

  const float* sp0 = src + (size_t)(r0 + kq0 * 4) * DIM + c0 + q * 4;
  const float* sp1 = sp0 + (size_t)64 * DIM;
  float4 v0 = *(const float4*)(sp0 + 0 * DIM);
  float4 v1 = *(const float4*)(sp0 + 1 * DIM);
  float4 v2 = *(const float4*)(sp0 + 2 * DIM);
  float4 v3 = *(const float4*)(sp0 + 3 * DIM);
  float4 v4 = *(const float4*)(sp1 + 0 * DIM);
  float4 v5 = *(const float4*)(sp1 + 1 * DIM);
  float4 v6 = *(const float4*)(sp1 + 2 * DIM);
  float4 v7 = *(const float4*)(sp1 + 3 * DIM);
  {
    float a0[4] = {v0.x, v0.y, v0.z, v0.w};
    float a1[4] = {v1.x, v1.y, v1.z, v1.w};
    float a2[4] = {v2.x, v2.y, v2.z, v2.w};
    float a3[4] = {v3.x, v3.y, v3.z, v3.w};
    float b0[4] = {v4.x, v4.y, v4.z, v4.w};
    float b1[4] = {v5.x, v5.y, v5.z, v5.w};
    float b2[4] = {v6.x, v6.y, v6.z, v6.w};
    float b3[4] = {v7.x, v7.y, v7.z, v7.w};
#pragma unroll
    for (int j = 0; j < 4; j++) {
      int row = q * 4 + j;
      {
        int kq = kq0;
        int ch = kq >> 1, half = kq & 1;
        unsigned int off = (unsigned int)row * 128 + ((ch ^ (row & 15)) * 8 + half * 4);
        uint2 p;
        p.x = f2bf(a0[j]) | ((unsigned int)f2bf(a1[j]) << 16);
        p.y = f2bf(a2[j]) | ((unsigned int)f2bf(a3[j]) << 16);
        *(uint2*)(lds + off) = p;
      }
      {
        int kq = kq0 + 16;
        int ch = kq >> 1, half = kq & 1;
        unsigned int off = (unsigned int)row * 128 + ((ch ^ (row & 15)) * 8 + half * 4);
        uint2 p;
        p.x = f2bf(b0[j]) | ((unsigned int)f2bf(b1[j]) << 16);
        p.y = f2bf(b2[j]) | ((unsigned int)f2bf(b3[j]) << 16);
        *(uint2*)(lds + off) = p;
      }
    }
  }
  __syncthreads();

  size_t bbase = ((size_t)n_blk * 32 + (size_t)k_blk * 4) * 4096;
#pragma unroll
  for (int i = 0; i < 4; i++) {
    int g = tid + i * 512;
    int kcr = g >> 9;
    int c = g & 511;
    int row = c >> 2, p = c & 3;
    int koff = (p - (row >> 1)) & 3;
    int ch = kcr * 4 + koff;
    uint4 val = *(const uint4*)(lds + (unsigned int)row * 128 + (ch ^ (row & 15)) * 8);
    *(uint4*)(dst + bbase + (size_t)g * 8) = val;
  }
}

// ---------------- K1: router (blocks 0..255) ∪ transpose(w1,w3,w1s,w3s) ------------------------
__global__ __launch_bounds__(512) void t13_router(
    const float* __restrict__ x, const float* __restrict__ gw,
    const float* __restrict__ w1, const float* __restrict__ w3,
    const float* __restrict__ w1s, const float* __restrict__ w3s,
    unsigned short* __restrict__ w1t, unsigned short* __restrict__ w3t,
    unsigned short* __restrict__ w1st, unsigned short* __restrict__ w3st,
    unsigned short* __restrict__ xbf,
    int* __restrict__ e0, int* __restrict__ e1,
    float* __restrict__ s0, float* __restrict__ s1) {
  __shared__ __align__(16) unsigned short lds[128 * 128];
  int b = blockIdx.x;
  if (b < 256) {
    int lane = threadIdx.x & 63;
    int t = b * 8 + (threadIdx.x >> 6);
    const float4* xr4 = (const float4*)(x + (size_t)t * DIM);
    float4 xv[4];
#pragma unroll
    for (int i = 0; i < 4; i++) xv[i] = xr4[i * 64 + lane];

    ushort4* xb4 = (ushort4*)(xbf + (size_t)t * DIM);
#pragma unroll
    for (int i = 0; i < 4; i++) {
      ushort4 o;
      o.x = f2bf(xv[i].x); o.y = f2bf(xv[i].y); o.z = f2bf(xv[i].z); o.w = f2bf(xv[i].w);
      xb4[i * 64 + lane] = o;
    }
    if (t == 0) {
      ushort4 zz; zz.x = zz.y = zz.z = zz.w = 0;
      ushort4* pb4 = (ushort4*)(xbf + (size_t)NTOK * DIM);
#pragma unroll
      for (int i = 0; i < 4; i++) pb4[i * 64 + lane] = zz;
    }

    float acc[NEXP];
#pragma unroll
    for (int e = 0; e < NEXP; e++) {
      const float4* g4 = (const float4*)(gw + (size_t)e * DIM);
      float a = 0.f;
#pragma unroll
      for (int i = 0; i < 4; i++) {
        float4 g = g4[i * 64 + lane];
        a += xv[i].x * g.x + xv[i].y * g.y + xv[i].z * g.z + xv[i].w * g.w;
      }
      acc[e] = a;
    }
#pragma unroll
    for (int e = 0; e < NEXP; e++) {
      float v = acc[e];
      for (int o = 32; o > 0; o >>= 1) v += __shfl_xor(v, o);
      acc[e] = v;
    }
    if (lane == 0) {
      float m = acc[0];
#pragma unroll
      for (int e = 1; e < NEXP; e++) m = fmaxf(m, acc[e]);
      float ex[NEXP]; float Z = 0.f;
#pragma unroll
      for (int e = 0; e < NEXP; e++) { ex[e] = __expf(acc[e] - m); Z += ex[e]; }
      float inv = 1.f / Z;
      float sc[NEXP];
#pragma unroll
      for (int e = 0; e < NEXP; e++) sc[e] = ex[e] * inv;
      int b0 = 0; float v0 = sc[0];
#pragma unroll
      for (int e = 1; e < NEXP; e++) if (sc[e] > v0) { v0 = sc[e]; b0 = e; }
      int b1 = -1; float v1 = -1.f;
#pragma unroll
      for (int e = 0; e < NEXP; e++) if (e != b0 && sc[e] > v1) { v1 = sc[e]; b1 = e; }
      e0[t] = b0; e1[t] = b1; s0[t] = v0; s1[t] = v1;
    }
  } else {
    int bb = b - 256;
    int slice = bb >> 6, s6 = bb & 63;
    int n_blk = s6 & 7, k_blk = s6 >> 3;
    const float* src; unsigned short* dst;
    if (slice < 8)       { src = w1 + (size_t)slice * MM;       dst = w1t + (size_t)slice * MM; }
    else if (slice < 16) { src = w3 + (size_t)(slice - 8) * MM; dst = w3t + (size_t)(slice - 8) * MM; }
    else if (slice == 16){ src = w1s; dst = w1st; }
    else                 { src = w3s; dst = w3st; }
    brick_transpose(src, dst, n_blk, k_blk, lds);
  }
}

// ---------------- deterministic grouped build: packed uint4 scan (128-row padding) -------------
__global__ __launch_bounds__(256) void build_groups(
    const int* __restrict__ e0, const int* __restrict__ e1,
    const float* __restrict__ s0, const float* __restrict__ s1,
    int* __restrict__ gtok, float* __restrict__ gsc, int* __restrict__ row_of,
    int* __restrict__ tile_e, int* __restrict__ tile_r0, int* __restrict__ ntiles,
    int* __restrict__ base8out) {
  __shared__ unsigned int wsum[4][4];
  __shared__ int offl[256][NEXP];
  __shared__ int lrl[256][NEXP];
  int t = threadIdx.x, lane = t & 63, wave = t >> 6;

  for (int i = t; i < ROWS_CAP; i += 256) { gtok[i] = NTOK; gsc[i] = 0.f; }

  unsigned int pc[4] = {0, 0, 0, 0};
#pragma unroll
  for (int i = 0; i < 16; i++) {
    int ent = t * 16 + i;
    int tok = ent >> 1;
    int e = (ent & 1) ? e1[tok] : e0[tok];
    unsigned int add = 1u << ((e & 1) * 16);
    int c = e >> 1;
    if (c == 0) pc[0] += add; else if (c == 1) pc[1] += add;
    else if (c == 2) pc[2] += add; else pc[3] += add;
  }
  unsigned int incl[4] = {pc[0], pc[1], pc[2], pc[3]};
#pragma unroll
  for (int o = 1; o < 64; o <<= 1) {
    unsigned int u0 = __shfl_up(incl[0], o), u1 = __shfl_up(incl[1], o);
    unsigned int u2 = __shfl_up(incl[2], o), u3 = __shfl_up(incl[3], o);
    if (lane >= o) { incl[0] += u0; incl[1] += u1; incl[2] += u2; incl[3] += u3; }
  }
  if (lane == 63) { wsum[wave][0] = incl[0]; wsum[wave][1] = incl[1];
                    wsum[wave][2] = incl[2]; wsum[wave][3] = incl[3]; }
  __syncthreads();
  unsigned int T[4], pre[4] = {0, 0, 0, 0};
#pragma unroll
  for (int c = 0; c < 4; c++)
    T[c] = wsum[0][c] + wsum[1][c] + wsum[2][c] + wsum[3][c];
#pragma unroll
  for (int w = 0; w < 3; w++)
    if (wave > w) { pre[0] += wsum[w][0]; pre[1] += wsum[w][1];
                    pre[2] += wsum[w][2]; pre[3] += wsum[w][3]; }
  int base[NEXP + 1];
  {
    int b = 0;
#pragma unroll
    for (int e = 0; e < NEXP; e++) {
      int tot = (int)((T[e >> 1] >> ((e & 1) * 16)) & 0xFFFFu);
      base[e] = b; b += (tot + 127) & ~127;
    }
    base[NEXP] = b;
  }
#pragma unroll
  for (int e = 0; e < NEXP; e++) {
    unsigned int ex = (incl[e >> 1] + pre[e >> 1] - pc[e >> 1]);
    offl[t][e] = (int)((ex >> ((e & 1) * 16)) & 0xFFFFu);
    lrl[t][e] = 0;
  }
  if (t == 0) {
    int nt = 0;
#pragma unroll
    for (int e = 0; e < NEXP; e++) {
      int tot = (int)((T[e >> 1] >> ((e & 1) * 16)) & 0xFFFFu);
      int ntl = (tot + 127) >> 7;
      for (int i = 0; i < ntl; i++) { tile_e[nt] = e; tile_r0[nt] = base[e] + i * 128; nt++; }
    }
    for (int i = 0; i < NTOK / 128; i++) { tile_e[nt] = NEXP; tile_r0[nt] = base[NEXP] + i * 128; nt++; }
    *ntiles = nt;
    *base8out = base[NEXP];
  }
  __syncthreads();

#pragma unroll
  for (int i = 0; i < 16; i++) {
    int ent = t * 16 + i;
    int tok = ent >> 1;
    int k = ent & 1;
    int e = k ? e1[tok] : e0[tok];
    float s = k ? s1[tok] : s0[tok];
    int pos = base[e] + offl[t][e] + lrl[t][e];
    lrl[t][e]++;
    gtok[pos] = tok; gsc[pos] = s; row_of[ent] = pos;
  }
  for (int i = t; i < NTOK; i += 256) { gtok[base[NEXP] + i] = i; gsc[base[NEXP] + i] = 1.0f; }
}

// ---------------- K3: gemm13 BK=64 (blocks 0..511) ∪ transpose(w2,w2s) -------------------------
// LDS: As/Bs1/Bs3 each 2 planes x [128][32] bf16 (16KB); plane h holds 32-k window h.
// Waves 64x32 (wrow=(wave>>2)*64, wcol=(wave&3)*32): acc[4][2] per B.
__global__ __launch_bounds__(512, 4) void gemm13_t2(
    const unsigned short* __restrict__ xbf,
    const unsigned short* __restrict__ W1, const unsigned short* __restrict__ W1s,
    const unsigned short* __restrict__ W3, const unsigned short* __restrict__ W3s,
    const float* __restrict__ w2, const float* __restrict__ w2s,
    unsigned short* __restrict__ w2t, unsigned short* __restrict__ w2st,
    unsigned short* __restrict__ H,
    const int* __restrict__ gtok, const float* __restrict__ gsc,
    const int* __restrict__ tile_e, const int* __restrict__ tile_r0,
    const int* __restrict__ ntiles) {
  __shared__ __align__(16) char smem[49664];   // union: 32KB transpose | 48.5KB gemm13
  int b = blockIdx.x;
  if (b >= 512) {
    int bb = b - 512;
    int slice = bb >> 6, s6 = bb & 63;
    int n_blk = s6 & 7, k_blk = s6 >> 3;
    const float* src; unsigned short* dst;
    if (slice < 8) { src = w2 + (size_t)slice * MM; dst = w2t + (size_t)slice * MM; }
    else           { src = w2s; dst = w2st; }
    brick_transpose(src, dst, n_blk, k_blk, (unsigned short*)smem);
    return;
  }
  int ti = b >> 3;
  if (ti >= *ntiles) return;
  int e = tile_e[ti];
  int row0 = tile_r0[ti];
  int col0 = (b & 7) * 128;
  const unsigned short* B1 = (e < NEXP) ? (W1 + (size_t)e * MM) : W1s;
  const unsigned short* B3 = (e < NEXP) ? (W3 + (size_t)e * MM) : W3s;

  unsigned short* As  = (unsigned short*)smem;            // 16KB (2 planes)
  unsigned short* Bs1 = (unsigned short*)(smem + 16384);  // 16KB
  unsigned short* Bs3 = (unsigned short*)(smem + 32768);  // 16KB
  float* ss = (float*)(smem + 49152);                     // 512B

  int tid = threadIdx.x;
  int wave = tid >> 6, lane = tid & 63;
  int wrow = (wave >> 2) * 64, wcol = (wave & 3) * 32;

  if (tid < 128) ss[tid] = gsc[row0 + tid];   // synced by first K-loop barrier

  f32x4 acc1[4][2], acc3[4][2];
#pragma unroll
  for (int m = 0; m < 4; m++)
#pragma unroll
    for (int n = 0; n < 2; n++) { acc1[m][n] = f32x4{0.f,0.f,0.f,0.f}; acc3[m][n] = f32x4{0.f,0.f,0.f,0.f}; }

  // A gather: plane chunk tid -> row=tid>>2, pos=tid&3 holding data chunk (pos-(row>>1))&3
  int arow = tid >> 2;
  int akoff = (((tid & 3) - (arow >> 1)) & 3) * 8;
  const unsigned short* ga  = xbf + (size_t)gtok[row0 + arow] * DIM + akoff;
  // B: linear brick reads; brick stride 4096 shorts = one plane
  const unsigned short* gb1 = B1 + ((size_t)(col0 >> 7) * 32) * 4096 + (size_t)tid * 8;
  const unsigned short* gb3 = B3 + ((size_t)(col0 >> 7) * 32) * 4096 + (size_t)tid * 8;
  unsigned short* lA  = As  + wave * 512;   // plane0 base; plane1 at +4096
  unsigned short* lB1 = Bs1 + wave * 512;
  unsigned short* lB3 = Bs3 + wave * 512;

  int kc = lane >> 4, rl = lane & 15;       // kc = within-plane chunk 0..3

  for (int it = 0; it < 16; it++) {
    int k0 = it * 64;
    size_t boff = (size_t)(it * 2) * 4096;
    gload_lds16(ga + k0,      lA);
    gload_lds16(ga + k0 + 32, lA + 4096);
    gload_lds16(gb1 + boff,        lB1);
    gload_lds16(gb1 + boff + 4096, lB1 + 4096);
    gload_lds16(gb3 + boff,        lB3);
    gload_lds16(gb3 + boff + 4096, lB3 + 4096);
    __syncthreads();   // drains vmcnt before use

#pragma unroll
    for (int h = 0; h < 2; h++) {
      const bf16x8* Ap  = (const bf16x8*)As  + h * 512;
      const bf16x8* B1p = (const bf16x8*)Bs1 + h * 512;
      const bf16x8* B3p = (const bf16x8*)Bs3 + h * 512;
      bf16x8 af[4], b1f[2], b3f[2];
#pragma unroll
      for (int m = 0; m < 4; m++) {
        int row = wrow + m * 16 + rl;
        af[m] = Ap[row * 4 + ((kc + (row >> 1)) & 3)];
      }
#pragma unroll
      for (int n = 0; n < 2; n++) {
        int row = wcol + n * 16 + rl;
        int p = row * 4 + ((kc + (row >> 1)) & 3);
        b1f[n] = B1p[p];
        b3f[n] = B3p[p];
      }
#pragma unroll
      for (int m = 0; m < 4; m++)
#pragma unroll
        for (int n = 0; n < 2; n++) {
          acc1[m][n] = __builtin_amdgcn_mfma_f32_16x16x32_bf16(af[m], b1f[n], acc1[m][n], 0, 0, 0);
          acc3[m][n] = __builtin_amdgcn_mfma_f32_16x16x32_bf16(af[m], b3f[n], acc3[m][n], 0, 0, 0);
        }
    }
    __syncthreads();   // before next stage overwrites LDS
  }

  int rj = lane >> 4, cl = lane & 15;
#pragma unroll
  for (int m = 0; m < 4; m++)
#pragma unroll
    for (int n = 0; n < 2; n++)
#pragma unroll
      for (int j = 0; j < 4; j++) {
        int lr = wrow + m * 16 + rj * 4 + j;
        float s = ss[lr];
        float a = s * acc1[m][n][j];
        float g = s * acc3[m][n][j];
        float si = a / (1.f + __expf(-a));
        H[(size_t)(row0 + lr) * DIM + (col0 + wcol + n * 16 + cl)] = f2bf(si * g);
      }
}

// ---------------- grouped GEMM BK=64: routb = H * W2_e (bf16 out); W2^T bricks -----------------
__global__ __launch_bounds__(512, 4) void gemm2(
    const unsigned short* __restrict__ A, const unsigned short* __restrict__ W,
    const unsigned short* __restrict__ Wsh, unsigned short* __restrict__ C,
    const int* __restrict__ tile_e, const int* __restrict__ tile_r0,
    const int* __restrict__ ntiles) {
  if ((int)blockIdx.y >= *ntiles) return;
  int e = tile_e[blockIdx.y];
  int row0 = tile_r0[blockIdx.y];
  int col0 = blockIdx.x * 128;
  const unsigned short* B = (e < NEXP) ? (W + (size_t)e * MM) : Wsh;

  __shared__ __align__(16) unsigned short As[2 * 4096];   // 2 planes x [128][32]
  __shared__ __align__(16) unsigned short Bs[2 * 4096];

  int tid = threadIdx.x;
  int wave = tid >> 6, lane = tid & 63;
  int wrow = (wave & 3) * 32, wcol = (wave >> 2) * 64;

  f32x4 acc[2][4];
#pragma unroll
  for (int m = 0; m < 2; m++)
#pragma unroll
    for (int n = 0; n < 4; n++) acc[m][n] = f32x4{0.f, 0.f, 0.f, 0.f};

  int arow = tid >> 2;
  int akoff = (((tid & 3) - (arow >> 1)) & 3) * 8;
  const unsigned short* ga = A + (size_t)(row0 + arow) * DIM + akoff;
  const unsigned short* gb = B + ((size_t)(col0 >> 7) * 32) * 4096 + (size_t)tid * 8;
  unsigned short* lA = As + wave * 512;
  unsigned short* lB = Bs + wave * 512;

  int kc = lane >> 4, rl = lane & 15;

  for (int it = 0; it < 16; it++) {
    int k0 = it * 64;
    size_t boff = (size_t)(it * 2) * 4096;
    gload_lds16(ga + k0,      lA);
    gload_lds16(ga + k0 + 32, lA + 4096);
    gload_lds16(gb + boff,        lB);
    gload_lds16(gb + boff + 4096, lB + 4096);
    __syncthreads();

#pragma unroll
    for (int h = 0; h < 2; h++) {
      const bf16x8* Ap = (const bf16x8*)As + h * 512;
      const bf16x8* Bp = (const bf16x8*)Bs + h * 512;
      bf16x8 af[2], bfr[4];
#pragma unroll
      for (int m = 0; m < 2; m++) {
        int row = wrow + m * 16 + rl;
        af[m] = Ap[row * 4 + ((kc + (row >> 1)) & 3)];
      }
#pragma unroll
      for (int n = 0; n < 4; n++) {
        int row = wcol + n * 16 + rl;
        bfr[n] = Bp[row * 4 + ((kc + (row >> 1)) & 3)];
      }
#pragma unroll
      for (int m = 0; m < 2; m++)
#pragma unroll
        for (int n = 0; n < 4; n++)
          acc[m][n] = __builtin_amdgcn_mfma_f32_16x16x32_bf16(af[m], bfr[n], acc[m][n], 0, 0, 0);
    }
    __syncthreads();
  }

  int rj = lane >> 4, cl = lane & 15;
#pragma unroll
  for (int m = 0; m < 2; m++)
#pragma unroll
    for (int n = 0; n < 4; n++)
#pragma unroll
      for (int j = 0; j < 4; j++) {
        int r = row0 + wrow + m * 16 + rj * 4 + j;
        int c = col0 + wcol + n * 16 + cl;
        C[(size_t)r * DIM + c] = f2bf(acc[m][n][j]);
      }
}

// ---------------- combine: out[t] = routb[r0] + routb[r1] + routb[shared] (bf16 in) ------------
__global__ __launch_bounds__(256) void combine(const unsigned short* __restrict__ routb,
                                               const int* __restrict__ row_of,
                                               const int* __restrict__ base8,
                                               float* __restrict__ out) {
  int t = blockIdx.x;
  int c = threadIdx.x * 4;
  int r0 = row_of[2 * t], r1 = row_of[2 * t + 1];
  int rs = *base8 + t;
  ushort4 v0 = *(const ushort4*)(routb + (size_t)r0 * DIM + c);
  ushort4 v1 = *(const ushort4*)(routb + (size_t)r1 * DIM + c);
  ushort4 v2 = *(const ushort4*)(routb + (size_t)rs * DIM + c);
  float4 o;
  o.x = bf2f(v0.x) + bf2f(v1.x) + bf2f(v2.x);
  o.y = bf2f(v0.y) + bf2f(v1.y) + bf2f(v2.y);
  o.z = bf2f(v0.z) + bf2f(v1.z) + bf2f(v2.z);
  o.w = bf2f(v0.w) + bf2f(v1.w) + bf2f(v2.w);
  *(float4*)(out + (size_t)t * DIM + c) = o;
}

extern "C" void kernel_launch(void* const* d_in, const int* in_sizes, int n_in,
                              void* d_out, int out_size, void* d_ws, size_t ws_size,
                              hipStream_t stream) {
  const float* x   = (const float*)d_in[0];
  const float* gw  = (const float*)d_in[1];
  const float* w1  = (const float*)d_in[2];
  const float* w2  = (const float*)d_in[3];
  const float* w3  = (const float*)d_in[4];
  const float* w1s = (const float*)d_in[5];
  const float* w2s = (const float*)d_in[6];
  const float* w3s = (const float*)d_in[7];
  float* out = (float*)d_out;
  char* ws = (char*)d_ws;

  const size_t MB = 1ull << 20;
  unsigned short* w1t  = (unsigned short*)(ws + 0 * MB);    // 16MB [8] brick-layout W1^T
  unsigned short* w3t  = (unsigned short*)(ws + 16 * MB);   // 16MB
  unsigned short* w2t  = (unsigned short*)(ws + 32 * MB);   // 16MB
  unsigned short* w1st = (unsigned short*)(ws + 48 * MB);   // 2MB
  unsigned short* w3st = (unsigned short*)(ws + 50 * MB);   // 2MB
  unsigned short* w2st = (unsigned short*)(ws + 52 * MB);   // 2MB
  unsigned short* xbf  = (unsigned short*)(ws + 54 * MB);   // 4MB+  [NTOK+1][1024] bf16
  unsigned short* hbuf = (unsigned short*)(ws + 60 * MB);   // 16MB [8192][1024] bf16
  unsigned short* routb= (unsigned short*)(ws + 76 * MB);   // 16MB [8192][1024] bf16
  char* meta = ws + 108 * MB;
  int*   e0p    = (int*)meta;
  int*   e1p    = e0p + NTOK;
  float* s0p    = (float*)(e1p + NTOK);
  float* s1p    = s0p + NTOK;
  int*   gtok   = (int*)(s1p + NTOK);
  float* gsc    = (float*)(gtok + ROWS_CAP);
  int*   row_of = (int*)(gsc + ROWS_CAP);
  int*   tile_e = row_of + NENT;
  int*   tile_r0= tile_e + MAX_TILES;
  int*   ntiles = tile_r0 + MAX_TILES;
  int*   base8  = ntiles + 1;

  // K1: router (256 blocks) ∪ transpose w1/w3/w1s/w3s (1152 blocks)
  t13_router<<<256 + 18 * 64, 512, 0, stream>>>(
      x, gw, w1, w3, w1s, w3s, w1t, w3t, w1st, w3st, xbf, e0p, e1p, s0p, s1p);
  // K2: deterministic group build
  build_groups<<<1, 256, 0, stream>>>(e0p, e1p, s0p, s1p, gtok, gsc, row_of,
                                      tile_e, tile_r0, ntiles, base8);
  // K3: gemm13 BK=64 (512 blocks) ∪ transpose w2/w2s (576 blocks)
  gemm13_t2<<<512 + 9 * 64, 512, 0, stream>>>(
      xbf, w1t, w1st, w3t, w3st, w2, w2s, w2t, w2st, hbuf,
      gtok, gsc, tile_e, tile_r0, ntiles);
  // K4: gemm2 BK=64 (bf16 out)
  dim3 gg(8, MAX_TILES);
  gemm2<<<gg, 512, 0, stream>>>(hbuf, w2t, w2st, routb, tile_e, tile_r0, ntiles);
  // K5: combine
  combine<<<NTOK, 256, 0, stream>>>(routb, row_of, base8, out);
}